// Round 17
// baseline (356.677 us; speedup 1.0000x reference)
//
#include <hip/hip_runtime.h>
#include <hip/hip_bf16.h>
#include <stdint.h>

// Transformer block for MI355X (gfx950).
// B=2 S=2048 D=1024 H=16 HD=64 E=8 K=2 HM=HS=1024, fp32 in/out, bf16 MFMA compute.
// Base: R10 proven config (353 us) + split-K=2 on the eo GEMM (grid-starvation fix).

typedef __hip_bfloat16 bf16;
typedef __attribute__((ext_vector_type(8))) __bf16 bf16x8;
typedef __attribute__((ext_vector_type(4))) float f32x4;
typedef __attribute__((ext_vector_type(16))) float f32x16;
typedef __attribute__((ext_vector_type(2))) unsigned int u32x2;

#define S_  2048
#define D_  1024
#define N_  4096      // B*S

__device__ __forceinline__ float b2f(bf16 h) { return __bfloat162float(h); }
__device__ __forceinline__ bf16  f2b(float f) { return __float2bfloat16(f); }

__device__ __forceinline__ bf16x8 ld_bf16x8(const bf16* p) {
    union { uint4 u; bf16x8 v; } x;
    x.u = *(const uint4*)p;
    return x.v;
}

__device__ __forceinline__ void gload_lds16(const void* gsrc, void* ldst) {
    __builtin_amdgcn_global_load_lds(
        (__attribute__((address_space(1))) void*)const_cast<void*>(gsrc),
        (__attribute__((address_space(3))) void*)ldst, 16, 0, 0);
}

// gfx950 LDS transpose read (per-lane addr = base + 8*lane).
__device__ __forceinline__ u32x2 tr16_read(unsigned lds_off) {
    u32x2 d;
    asm volatile("ds_read_b64_tr_b16 %0, %1" : "=v"(d) : "v"(lds_off));
    return d;
}

// granule swizzle for [row][32] bf16 LDS tiles (64B rows, 4x16B granules).
__device__ __forceinline__ int swz4(int r) { return ((r >> 1) ^ (r >> 3)) & 3; }

// ---------------------------------------------------------------------------
// All weight transposes (fp32 -> bf16) in ONE launch. grid (16,16,31).
// ---------------------------------------------------------------------------
__global__ __launch_bounds__(256)
void transpose_all(const float* __restrict__ wq, const float* __restrict__ wk,
                   const float* __restrict__ wv, const float* __restrict__ wo,
                   const float* __restrict__ ew1, const float* __restrict__ ew2,
                   const float* __restrict__ ew3, const float* __restrict__ sw1,
                   const float* __restrict__ sw2, const float* __restrict__ sw3,
                   bf16* __restrict__ wqkv_t, bf16* __restrict__ wo_t,
                   bf16* __restrict__ ew13_t, bf16* __restrict__ ew2_t)
{
    __shared__ float t[64][65];
    const int z = blockIdx.z;
    const float* in; bf16* out; int rm = 1, ro = 0;
    if (z < 3)        { in = (z == 0 ? wq : z == 1 ? wk : wv); out = wqkv_t + (size_t)z * 1048576; }
    else if (z == 3)  { in = wo; out = wo_t; }
    else if (z < 12)  { const int e = z - 4;  in = ew1 + (size_t)e * 1048576; out = ew13_t + (size_t)e * 2097152; rm = 2; ro = 0; }
    else if (z < 20)  { const int e = z - 12; in = ew3 + (size_t)e * 1048576; out = ew13_t + (size_t)e * 2097152; rm = 2; ro = 1; }
    else if (z < 28)  { const int e = z - 20; in = ew2 + (size_t)e * 1048576; out = ew2_t + (size_t)e * 1048576; }
    else if (z == 28) { in = sw1; out = ew13_t + (size_t)8 * 2097152; rm = 2; ro = 0; }
    else if (z == 29) { in = sw3; out = ew13_t + (size_t)8 * 2097152; rm = 2; ro = 1; }
    else              { in = sw2; out = ew2_t + (size_t)8 * 1048576; }

    const int c0 = blockIdx.x * 64, r0 = blockIdx.y * 64;
    const int tx = (threadIdx.x & 15) * 4, ty = threadIdx.x >> 4;   // ty 0..15
#pragma unroll
    for (int i = 0; i < 4; i++)
        *(float4*)&t[ty + i * 16][tx] = *(const float4*)(in + (size_t)(r0 + ty + i * 16) * 1024 + c0 + tx);
    __syncthreads();
#pragma unroll
    for (int i = 0; i < 4; i++) {
        const int lc = ty + i * 16;
        union { bf16 h[4]; uint2 u; } pk;
#pragma unroll
        for (int j = 0; j < 4; j++) pk.h[j] = f2b(t[tx + j][lc]);
        *(uint2*)&out[(size_t)((c0 + lc) * rm + ro) * 1024 + r0 + tx] = pk.u;
    }
}

// ---------------------------------------------------------------------------
// RMSNorm: fp32 in -> bf16 out.  grid N_, block 256
// ---------------------------------------------------------------------------
__global__ __launch_bounds__(256)
void rmsnorm_kernel(const float* __restrict__ x, const float* __restrict__ w,
                    bf16* __restrict__ out)
{
    const int n = blockIdx.x;
    const int tid = threadIdx.x;
    const float4 v = *(const float4*)(x + (size_t)n * D_ + tid * 4);
    float ss = v.x * v.x + v.y * v.y + v.z * v.z + v.w * v.w;
#pragma unroll
    for (int m = 1; m < 64; m <<= 1) ss += __shfl_xor(ss, m);
    __shared__ float red[4];
    if ((tid & 63) == 0) red[tid >> 6] = ss;
    __syncthreads();
    const float tot = red[0] + red[1] + red[2] + red[3];
    const float rstd = rsqrtf(tot * (1.0f / D_) + 1e-6f);
    const float4 wv = *(const float4*)(w + tid * 4);
    union { bf16 h[4]; uint2 u; } pk;
    pk.h[0] = f2b(v.x * rstd * wv.x);
    pk.h[1] = f2b(v.y * rstd * wv.y);
    pk.h[2] = f2b(v.z * rstd * wv.z);
    pk.h[3] = f2b(v.w * rstd * wv.w);
    *(uint2*)(out + (size_t)n * D_ + tid * 4) = pk.u;
}

// ---------------------------------------------------------------------------
// GEMM: C[M][N] = A[M][K] * Bt[N][K]^T  (A,Bt bf16 row-major; acc fp32)
// 128x128 tile, BK=32, 512 threads = 8 waves (2Mx4N), 64x32/wave.
// PROVEN 353us config (R10): acc = 2x f32x16 = 32 regs; LDS 32 KB.
// Counted-vmcnt depth-1: issue next tile (1 A + 1 B gload/thread), vmcnt(2),
// s_barrier, compute (4x mfma_32x32x16), s_barrier. Source-granule swz4.
// C layout (m74/m101): row=(i&3)+8*(i>>2)+4*(lane>>5), col=lane&31.
// XCD swizzle ONLY for MODE==0 (grouped early-exit + swizzle = R4/R5 bug).
// EPI: 0 = store bf16, 1 = store fp32, 2 = fp32 resid add,
//      3 = swiglu pair -> bf16, 4 = fused RoPE (qkv layout, ldc=3072)
// MODE: 0 = plain, 1 = grouped+gathered A rows (token_list),
//       2 = grouped contiguous,
//       3 = grouped contiguous + SPLIT-K=2 (z = e*2+kh; K range kh*512..+512;
//           kh=0 partial -> Cout, kh=1 partial -> Cout2; bf16; combine sums).
// ---------------------------------------------------------------------------
template<int EPI, int MODE>
__global__ __launch_bounds__(512)
void gemm_bt(const bf16* __restrict__ A, const bf16* __restrict__ Bt,
             void* __restrict__ Cout, const float* __restrict__ resid,
             int M, int Kdim, int lda, int ldb, int ldc, long bstride,
             const int* __restrict__ tlist, const int* __restrict__ offs,
             const float* __restrict__ fc, const float* __restrict__ fs,
             void* __restrict__ Cout2)
{
    __shared__ bf16 As[2][128 * 32];
    __shared__ bf16 Bs[2][128 * 32];
    const int tid = threadIdx.x;
    const int wave = tid >> 6, lane = tid & 63;

    int bx, by;
    if constexpr (MODE == 0) {
        const int gx = gridDim.x;
        const int nwg = gx * gridDim.y;
        int flat = blockIdx.y * gx + blockIdx.x;
        flat = (flat & 7) * (nwg >> 3) + (flat >> 3);
        bx = flat % gx; by = flat / gx;
    } else {
        bx = blockIdx.x; by = blockIdx.y;
    }

    int mcount = M, outBase = 0, kh = 0;
    const bf16* Bp = Bt;
    if (MODE != 0) {
        int e;
        if constexpr (MODE == 3) { e = blockIdx.z >> 1; kh = blockIdx.z & 1; }
        else                     { e = blockIdx.z; }
        outBase = offs[e];
        mcount = offs[e + 1] - outBase;
        Bp = Bt + (size_t)e * bstride;
    }
    const int m0 = by * 128;
    if (m0 >= mcount) return;
    const int n0 = bx * 128;
    const int koff = kh * 512;   // MODE 3 K-half offset (0 otherwise)

    // staging: 1 A-load + 1 B-load per thread. row = tid>>2 (0..127),
    // LDS slot granule = tid&3; SOURCE granule pre-swizzled (slot^swz4(row)).
    // LDS dest byte = row*64 + slot*16 = tid*16 = wave*1024 + lane*16 (linear).
    const int srow = tid >> 2;
    const int sc4 = tid & 3;
    const int scol = (sc4 ^ swz4(srow)) * 8;
    int rA = m0 + srow;
    if (rA >= mcount) rA = mcount - 1;
    long arow;
    if (MODE == 1)                    arow = tlist[outBase + rA];
    else if (MODE == 2 || MODE == 3)  arow = (long)outBase + rA;
    else                              arow = rA;
    const bf16* aptr = A + (size_t)arow * lda + koff + scol;
    const bf16* bptr = Bp + (size_t)(n0 + srow) * ldb + koff + scol;

    f32x16 acc[2];
#pragma unroll
    for (int tm = 0; tm < 2; tm++)
#pragma unroll
        for (int i = 0; i < 16; i++) acc[tm][i] = 0.f;

    const int wm = (wave >> 2) * 64, wn = (wave & 3) * 32;
    const int l31 = lane & 31, l5 = lane >> 5;

    // fragment LDS element offsets (slot = granule ^ swz4(row))
    int aoff[2][2], boff[2];
#pragma unroll
    for (int tm = 0; tm < 2; tm++) {
        const int ra = wm + tm * 32 + l31;
#pragma unroll
        for (int kk = 0; kk < 2; kk++)
            aoff[tm][kk] = ra * 32 + ((kk * 2 + l5) ^ swz4(ra)) * 8;
    }
    {
        const int rb = wn + l31;
#pragma unroll
        for (int kk = 0; kk < 2; kk++)
            boff[kk] = rb * 32 + ((kk * 2 + l5) ^ swz4(rb)) * 8;
    }

    const int nkt = Kdim >> 5;
    // prologue: stage tile 0 into buffer 0
    gload_lds16(aptr, (char*)&As[0][0] + wave * 1024);
    gload_lds16(bptr, (char*)&Bs[0][0] + wave * 1024);

    int p = 0;
    for (int kt = 0; kt < nkt; kt++) {
        if (kt + 1 < nkt) {
            const int ko = (kt + 1) << 5;
            gload_lds16(aptr + ko, (char*)&As[p ^ 1][0] + wave * 1024);
            gload_lds16(bptr + ko, (char*)&Bs[p ^ 1][0] + wave * 1024);
            asm volatile("s_waitcnt vmcnt(2)" ::: "memory");   // FIFO: current buffer landed
        } else {
            asm volatile("s_waitcnt vmcnt(0)" ::: "memory");
        }
        asm volatile("s_barrier" ::: "memory");

        const bf16* Ab = &As[p][0];
        const bf16* Bb = &Bs[p][0];
#pragma unroll
        for (int kk = 0; kk < 2; kk++) {
            const bf16x8 bf0 = ld_bf16x8(&Bb[boff[kk]]);
            const bf16x8 af0 = ld_bf16x8(&Ab[aoff[0][kk]]);
            const bf16x8 af1 = ld_bf16x8(&Ab[aoff[1][kk]]);
            acc[0] = __builtin_amdgcn_mfma_f32_32x32x16_bf16(af0, bf0, acc[0], 0, 0, 0);
            acc[1] = __builtin_amdgcn_mfma_f32_32x32x16_bf16(af1, bf0, acc[1], 0, 0, 0);
        }

        asm volatile("s_barrier" ::: "memory");
        p ^= 1;
    }

    // epilogue: row = (i&3) + 8*(i>>2) + 4*l5, col = l31 within each 32x32 tile
    bf16* dst0 = (bf16*)Cout;
    if (MODE == 3 && kh) dst0 = (bf16*)Cout2;
#pragma unroll
    for (int tm = 0; tm < 2; tm++)
#pragma unroll
        for (int i = 0; i < 16; i++) {
            const int r = m0 + wm + tm * 32 + (i & 3) + 8 * (i >> 2) + 4 * l5;
            const int c = n0 + wn + l31;
            const float v = acc[tm][i];
            if (EPI == 3) {
                const float other = __shfl_xor(v, 1);
                const float res = (v / (1.f + __expf(-v))) * other;  // silu(g1)*g3 on even lanes
                if (((lane & 1) == 0) && r < mcount)
                    ((bf16*)Cout)[(size_t)(outBase + r) * ldc + (c >> 1)] = f2b(res);
            } else if (EPI == 4) {
                // fused RoPE: c<1024 q (scale 1/8), c<2048 k, else v passthrough
                const float other = __shfl_xor(v, 1);
                float o = v;
                if (c < 2048) {
                    const int s = r & (S_ - 1);
                    const int jf = (c & 63) >> 1;
                    const float co = fc[s * 32 + jf], si = fs[s * 32 + jf];
                    o = v * co + other * ((c & 1) ? si : -si);
                    if (c < 1024) o *= 0.125f;   // fold 1/sqrt(HD) into q
                }
                ((bf16*)Cout)[(size_t)r * ldc + c] = f2b(o);
            } else if (r < mcount) {
                const size_t oi = (size_t)(outBase + r) * ldc + c;
                if (EPI == 0)      dst0[oi] = f2b(v);
                else if (EPI == 1) ((float*)Cout)[oi] = v;
                else               ((float*)Cout)[oi] = resid[oi] + v;
            }
        }
}

// ---------------------------------------------------------------------------
// Flash attention, non-causal, swapped-operand structure.
// grid (S/128, H=16, B=2), block 256 (4 waves, 32 q-rows/wave). KV tile = 64.
// ---------------------------------------------------------------------------
__global__ __launch_bounds__(256)
void attn_kernel(const bf16* __restrict__ qkv, bf16* __restrict__ out)
{
    __shared__ __align__(16) bf16 Ks[64 * 72];          // [kv][64 hd] pad 72
    __shared__ __align__(16) bf16 Vs[4 * 1032 + 8];     // [hd chunk][64 kv][16 hd], chunk stride 1032
    const int tid = threadIdx.x, wave = tid >> 6, lane = tid & 63;
    const int b = blockIdx.z, hh = blockIdx.y;
    const int q0 = blockIdx.x * 128;
    const bf16* base  = qkv + ((size_t)b * S_) * 3072 + (size_t)hh * 64;
    const bf16* kbase = base + 1024;
    const bf16* vbase = base + 2048;
    const int fr = lane & 15, fg = lane >> 4;

    // Q fragments (B-operand): lane holds q = fr, hd = fg*8.. (+32 per s2)
    bf16x8 aq[2][2];
#pragma unroll
    for (int qb = 0; qb < 2; qb++)
#pragma unroll
        for (int s2 = 0; s2 < 2; s2++)
            aq[qb][s2] = ld_bf16x8(base + (size_t)(q0 + wave * 32 + qb * 16 + fr) * 3072 + s2 * 32 + fg * 8);

    f32x4 zero4 = {0.f, 0.f, 0.f, 0.f};
    f32x4 acc_o[2][4];       // [qb][hf]: rows q = fg*4+j, cols hd = hf*16+fr
    float mrow[2], lrow[2];  // per-lane stats for q = fr
#pragma unroll
    for (int qb = 0; qb < 2; qb++) {
#pragma unroll
        for (int hf = 0; hf < 4; hf++) acc_o[qb][hf] = zero4;
        mrow[qb] = -1e30f; lrow[qb] = 0.f;
    }

    const int srow = tid >> 2, sc4 = tid & 3;
    const unsigned vtr0 =
        (unsigned)(uintptr_t)(__attribute__((address_space(3))) void*)&Vs[0] + lane * 8;

    // register-staged K/V prefetch (double-buffered against compute)
    uint4 kg0, kg1, vg0, vg1;
    {
        const bf16* kr = kbase + (size_t)srow * 3072 + sc4 * 16;
        kg0 = *(const uint4*)kr; kg1 = *(const uint4*)(kr + 8);
        const bf16* vr = vbase + (size_t)srow * 3072 + sc4 * 16;
        vg0 = *(const uint4*)vr; vg1 = *(const uint4*)(vr + 8);
    }

    for (int kv0 = 0; kv0 < S_; kv0 += 64) {
        __syncthreads();
        *(uint4*)&Ks[srow * 72 + sc4 * 16]         = kg0;
        *(uint4*)&Ks[srow * 72 + sc4 * 16 + 8]     = kg1;
        *(uint4*)&Vs[sc4 * 1032 + srow * 16]       = vg0;
        *(uint4*)&Vs[sc4 * 1032 + srow * 16 + 8]   = vg1;
        __syncthreads();
        if (kv0 + 64 < S_) {    // prefetch next tile (hides HBM under compute)
            const bf16* kr = kbase + (size_t)(kv0 + 64 + srow) * 3072 + sc4 * 16;
            kg0 = *(const uint4*)kr; kg1 = *(const uint4*)(kr + 8);
            const bf16* vr = vbase + (size_t)(kv0 + 64 + srow) * 3072 + sc4 * 16;
            vg0 = *(const uint4*)vr; vg1 = *(const uint4*)(vr + 8);
        }

        // ---- QK^T (swapped): sc[kt][qb] = K_tile(kt) x Q(qb), S^T layout ----
        f32x4 sc[4][2];
#pragma unroll
        for (int kt = 0; kt < 4; kt++)
#pragma unroll
            for (int qb = 0; qb < 2; qb++) sc[kt][qb] = zero4;
        __builtin_amdgcn_s_setprio(1);
#pragma unroll
        for (int kt = 0; kt < 4; kt++) {
            const bf16x8 k0 = ld_bf16x8(&Ks[(kt * 16 + fr) * 72 + fg * 8]);
            const bf16x8 k1 = ld_bf16x8(&Ks[(kt * 16 + fr) * 72 + 32 + fg * 8]);
#pragma unroll
            for (int qb = 0; qb < 2; qb++) {
                sc[kt][qb] = __builtin_amdgcn_mfma_f32_16x16x32_bf16(k0, aq[qb][0], sc[kt][qb], 0, 0, 0);
                sc[kt][qb] = __builtin_amdgcn_mfma_f32_16x16x32_bf16(k1, aq[qb][1], sc[kt][qb], 0, 0, 0);
            }
        }
        __builtin_amdgcn_s_setprio(0);

        // ---- online softmax, fully in-register (lane owns row q = fr) ----
        bf16x8 pcomb[2][2];   // [qb][tp]: A-operand P fragments (two 16-kv tiles packed)
        float scalv[2];
#pragma unroll
        for (int qb = 0; qb < 2; qb++) {
            float pm = -1e30f;
#pragma unroll
            for (int kt = 0; kt < 4; kt++)
#pragma unroll
                for (int j = 0; j < 4; j++) pm = fmaxf(pm, sc[kt][qb][j]);
            pm = fmaxf(pm, __shfl_xor(pm, 16));
            pm = fmaxf(pm, __shfl_xor(pm, 32));
            const float mnew = fmaxf(mrow[qb], pm);
            const float scal = __expf(mrow[qb] - mnew);
            mrow[qb] = mnew;
            float ps = 0.f;
            union { bf16 h[16]; bf16x8 v8[2]; } pk;
#pragma unroll
            for (int kt = 0; kt < 4; kt++)
#pragma unroll
                for (int j = 0; j < 4; j++) {
                    const float p = __expf(sc[kt][qb][j] - mnew);
                    ps += p;
                    pk.h[kt * 4 + j] = f2b(p);
                }
            pcomb[qb][0] = pk.v8[0];
            pcomb[qb][1] = pk.v8[1];
            ps += __shfl_xor(ps, 16);
            ps += __shfl_xor(ps, 32);
            lrow[qb] = lrow[qb] * scal + ps;
            scalv[qb] = scal;
        }

        // rescale O (its rows are q = fg*4+j -> fetch that q's scal)
#pragma unroll
        for (int j = 0; j < 4; j++) {
            const int src = (lane & 48) + fg * 4 + j;
            const float s0 = __shfl(scalv[0], src);
            const float s1 = __shfl(scalv[1], src);
#pragma unroll
            for (int hf = 0; hf < 4; hf++) {
                acc_o[0][hf][j] *= s0;
                acc_o[1][hf][j] *= s1;
            }
        }

        // ---- PV: B-operand via hw transpose-read, two 16-kv tiles per mfma ----
#pragma unroll
        for (int tp = 0; tp < 2; tp++) {
            union { u32x2 d2[2]; bf16x8 v8; } vc[4];
#pragma unroll
            for (int hf = 0; hf < 4; hf++) {
                vc[hf].d2[0] = tr16_read(vtr0 + hf * 2064 + (tp * 2)     * 512);
                vc[hf].d2[1] = tr16_read(vtr0 + hf * 2064 + (tp * 2 + 1) * 512);
            }
            asm volatile("s_waitcnt lgkmcnt(0)" ::: "memory");
            __builtin_amdgcn_sched_barrier(0);   // rule 18: keep MFMAs below the wait
            __builtin_amdgcn_s_setprio(1);
#pragma unroll
            for (int hf = 0; hf < 4; hf++)
#pragma unroll
                for (int qb = 0; qb < 2; qb++)
                    acc_o[qb][hf] = __builtin_amdgcn_mfma_f32_16x16x32_bf16(
                        pcomb[qb][tp], vc[hf].v8, acc_o[qb][hf], 0, 0, 0);
            __builtin_amdgcn_s_setprio(0);
        }
    }

    // ---- epilogue: out rows q = fg*4+j, cols hd = hf*16+fr ----
#pragma unroll
    for (int qb = 0; qb < 2; qb++) {
        const float inv = 1.f / lrow[qb];
#pragma unroll
        for (int j = 0; j < 4; j++) {
            const float ij = __shfl(inv, (lane & 48) + fg * 4 + j);
            const int r = q0 + wave * 32 + qb * 16 + fg * 4 + j;
#pragma unroll
            for (int hf = 0; hf < 4; hf++)
                out[((size_t)(b * S_ + r)) * D_ + hh * 64 + hf * 16 + fr] =
                    f2b(acc_o[qb][hf][j] * ij);
        }
    }
}

// ---------------------------------------------------------------------------
// MoE gating: fp32 scores from pre-norm h (recompute rmsnorm scale), top-2.
// ---------------------------------------------------------------------------
__global__ __launch_bounds__(256)
void gating_kernel(const float* __restrict__ h, const float* __restrict__ gw,
                   const float* __restrict__ wnorm,
                   int* __restrict__ top_idx, float* __restrict__ top_w)
{
    const int wave = threadIdx.x >> 6, lane = threadIdx.x & 63;
    const int n = blockIdx.x * 4 + wave;
    const float* hr = h + (size_t)n * D_;
    float acc[8] = {0.f, 0.f, 0.f, 0.f, 0.f, 0.f, 0.f, 0.f};
    float ss = 0.f;
    for (int d = lane * 4; d < D_; d += 256) {
        const float4 hv = *(const float4*)(hr + d);
        const float4 wv = *(const float4*)(wnorm + d);
        ss += hv.x * hv.x + hv.y * hv.y + hv.z * hv.z + hv.w * hv.w;
        const float x0 = hv.x * wv.x, x1 = hv.y * wv.y, x2 = hv.z * wv.z, x3 = hv.w * wv.w;
#pragma unroll
        for (int e2 = 0; e2 < 8; e2++) {
            const float4 gv = *(const float4*)(gw + e2 * D_ + d);
            acc[e2] += x0 * gv.x + x1 * gv.y + x2 * gv.z + x3 * gv.w;
        }
    }
#pragma unroll
    for (int m = 1; m < 64; m <<= 1) {
        ss += __shfl_xor(ss, m);
#pragma unroll
        for (int e2 = 0; e2 < 8; e2++) acc[e2] += __shfl_xor(acc[e2], m);
    }
    if (lane == 0) {
        const float rstd = rsqrtf(ss * (1.0f / D_) + 1e-6f);
        float s[8];
#pragma unroll
        for (int e2 = 0; e2 < 8; e2++) s[e2] = acc[e2] * rstd;
        int e0 = 0;
#pragma unroll
        for (int e2 = 1; e2 < 8; e2++) if (s[e2] > s[e0]) e0 = e2;
        int e1 = (e0 == 0) ? 1 : 0;
#pragma unroll
        for (int e2 = 0; e2 < 8; e2++) if (e2 != e0 && s[e2] > s[e1]) e1 = e2;
        const float mx = s[e0];
        float Z = 0.f;
        float p[8];
#pragma unroll
        for (int e2 = 0; e2 < 8; e2++) { p[e2] = __expf(s[e2] - mx); Z += p[e2]; }
        const float v0 = p[e0] / Z, v1 = p[e1] / Z;
        const float sm = v0 + v1 + 1e-9f;
        top_idx[n * 2] = e0; top_idx[n * 2 + 1] = e1;
        top_w[n * 2] = v0 / sm; top_w[n * 2 + 1] = v1 / sm;
    }
}

// ---------------------------------------------------------------------------
// Routing: single block, LDS atomics only. histogram -> offsets -> scatter.
// Adds the shared expert as slot 8: identity token list for all 4096 tokens.
// ---------------------------------------------------------------------------
__global__ __launch_bounds__(1024)
void route_kernel(const int* __restrict__ top_idx, int* __restrict__ offs,
                  int* __restrict__ token_list, int* __restrict__ tok_pos)
{
    __shared__ int hist[8];
    __shared__ int base[8];
    const int tid = threadIdx.x;
    if (tid < 8) hist[tid] = 0;
    __syncthreads();
    int4 e4a = *(const int4*)(top_idx + tid * 8);
    int4 e4b = *(const int4*)(top_idx + tid * 8 + 4);
    int myidx[8] = {e4a.x, e4a.y, e4a.z, e4a.w, e4b.x, e4b.y, e4b.z, e4b.w};
#pragma unroll
    for (int i = 0; i < 8; i++) atomicAdd(&hist[myidx[i]], 1);
    __syncthreads();
    if (tid == 0) {
        int o = 0;
#pragma unroll
        for (int e = 0; e < 8; e++) { base[e] = o; offs[e] = o; o += hist[e]; }
        offs[8] = o;          // == 8192 always
        offs[9] = o + N_;     // shared-expert segment
    }
    __syncthreads();
    if (tid < 8) hist[tid] = 0;
    __syncthreads();
#pragma unroll
    for (int i = 0; i < 8; i++) {
        const int entry = tid * 8 + i;
        const int e = myidx[i];
        const int pos = base[e] + atomicAdd(&hist[e], 1);
        token_list[pos] = entry >> 1;
        tok_pos[entry] = pos;
    }
    // shared expert (slot 8): identity gather over all tokens
#pragma unroll
    for (int i = 0; i < 4; i++)
        token_list[2 * N_ + tid * 4 + i] = tid * 4 + i;
}

// out = h + (eoA+eoB)[shared(n)] + w0*(eoA+eoB)[pos0] + w1*(eoA+eoB)[pos1]
// (eoA/eoB are the two split-K partial buffers)
__global__ __launch_bounds__(256)
void combine_kernel(const float* __restrict__ h, const bf16* __restrict__ eoA,
                    const bf16* __restrict__ eoB,
                    const int* __restrict__ tok_pos, const float* __restrict__ top_w,
                    float* __restrict__ out)
{
    const int idx = blockIdx.x * 256 + threadIdx.x;   // N_*D_/4 total
    const int n = idx >> 8;
    const int c = (idx & 255) * 4;
    const float4 hv = *(const float4*)(h + (size_t)n * D_ + c);
    const int p0 = tok_pos[n * 2], p1 = tok_pos[n * 2 + 1];
    const float w0 = top_w[n * 2], w1 = top_w[n * 2 + 1];
    union U { uint2 u; bf16 hh[4]; };
    U a0, a1, ash, b0, b1, bsh;
    a0.u  = *(const uint2*)(eoA + (size_t)p0 * D_ + c);
    a1.u  = *(const uint2*)(eoA + (size_t)p1 * D_ + c);
    ash.u = *(const uint2*)(eoA + (size_t)(2 * N_ + n) * D_ + c);
    b0.u  = *(const uint2*)(eoB + (size_t)p0 * D_ + c);
    b1.u  = *(const uint2*)(eoB + (size_t)p1 * D_ + c);
    bsh.u = *(const uint2*)(eoB + (size_t)(2 * N_ + n) * D_ + c);
    float4 r;
    r.x = hv.x + (b2f(ash.hh[0]) + b2f(bsh.hh[0]))
        + w0 * (b2f(a0.hh[0]) + b2f(b0.hh[0])) + w1 * (b2f(a1.hh[0]) + b2f(b1.hh[0]));
    r.y = hv.y + (b2f(ash.hh[1]) + b2f(bsh.hh[1]))
        + w0 * (b2f(a0.hh[1]) + b2f(b0.hh[1])) + w1 * (b2f(a1.hh[1]) + b2f(b1.hh[1]));
    r.z = hv.z + (b2f(ash.hh[2]) + b2f(bsh.hh[2]))
        + w0 * (b2f(a0.hh[2]) + b2f(b0.hh[2])) + w1 * (b2f(a1.hh[2]) + b2f(b1.hh[2]));
    r.w = hv.w + (b2f(ash.hh[3]) + b2f(bsh.hh[3]))
        + w0 * (b2f(a0.hh[3]) + b2f(b0.hh[3])) + w1 * (b2f(a1.hh[3]) + b2f(b1.hh[3]));
    *(float4*)(out + (size_t)n * D_ + c) = r;
}

// ---------------------------------------------------------------------------
extern "C" void kernel_launch(void* const* d_in, const int* in_sizes, int n_in,
                              void* d_out, int out_size, void* d_ws, size_t ws_size,
                              hipStream_t stream)
{
    const float* x   = (const float*)d_in[0];
    const float* fc  = (const float*)d_in[1];
    const float* fs  = (const float*)d_in[2];
    const float* anw = (const float*)d_in[3];
    const float* fnw = (const float*)d_in[4];
    const float* wq  = (const float*)d_in[5];
    const float* wk  = (const float*)d_in[6];
    const float* wv  = (const float*)d_in[7];
    const float* wo  = (const float*)d_in[8];
    const float* gw  = (const float*)d_in[9];
    const float* ew1 = (const float*)d_in[10];
    const float* ew2 = (const float*)d_in[11];
    const float* ew3 = (const float*)d_in[12];
    const float* sw1 = (const float*)d_in[13];
    const float* sw2 = (const float*)d_in[14];
    const float* sw3 = (const float*)d_in[15];

    char* ws = (char*)d_ws;
    bf16*  wqkv_t = (bf16*)(ws + 0);           //  6291456 B  [3072][1024]
    bf16*  wo_t   = (bf16*)(ws + 6291456);     //  2097152 B  [1024][1024]
    bf16*  ew13_t = (bf16*)(ws + 8388608);     // 37748736 B  9 x [2048][1024] interleaved (slot 8 = shared sw1/sw3)
                                               //   DEAD after h1 GEMM -> reused as eo partial-1 (25165824 B)
    bf16*  ew2_t  = (bf16*)(ws + 46137344);    // 18874368 B  9 x [1024][1024] (slot 8 = shared sw2)
    bf16*  xn     = (bf16*)(ws + 65011712);    //  8388608 B  [4096][1024]  (reused as xf)
    bf16*  qkv    = (bf16*)(ws + 73400320);    // 25165824 B  [4096][3072]  (reused as h1 [12288][1024])
    bf16*  attn   = (bf16*)(ws + 98566144);    //  8388608 B  [4096][1024]
    float* hbuf   = (float*)(ws + 106954752);  // 16777216 B  [4096][1024]
    bf16*  eo     = (bf16*)(ws + 123731968);   // 25165824 B  [12288][1024]  (split-K partial-0)
    bf16*  eo2    = ew13_t;                    // split-K partial-1 (overlays dead ew13_t)
    char*  misc   = ws + 148897792;
    int*   offs       = (int*)(misc + 0);              // 16 ints
    int*   top_idx    = (int*)(misc + 128);            // 8192 ints
    float* top_w      = (float*)(misc + 128 + 32768);  // 8192 floats
    int*   token_list = (int*)(misc + 128 + 65536);    // 12288 ints
    int*   tok_pos    = (int*)(misc + 128 + 131072);   // 8192 ints

    const dim3 tb(256);
    const dim3 tb512(512);
    // all weight transposes in one launch (64x64 tiles)
    transpose_all<<<dim3(16, 16, 31), tb, 0, stream>>>(
        wq, wk, wv, wo, ew1, ew2, ew3, sw1, sw2, sw3,
        wqkv_t, wo_t, ew13_t, ew2_t);

    // attention branch (RoPE fused into QKV epilogue)
    rmsnorm_kernel<<<N_, tb, 0, stream>>>(x, anw, xn);
    gemm_bt<4, 0><<<dim3(24, 32, 1), tb512, 0, stream>>>(xn, wqkv_t, qkv, nullptr,
        N_, 1024, 1024, 1024, 3072, 0, nullptr, nullptr, fc, fs, nullptr);
    attn_kernel<<<dim3(16, 16, 2), tb, 0, stream>>>(qkv, attn);
    gemm_bt<2, 0><<<dim3(8, 32, 1), tb512, 0, stream>>>(attn, wo_t, hbuf, x,
        N_, 1024, 1024, 1024, 1024, 0, nullptr, nullptr, nullptr, nullptr, nullptr);

    // FFN branch
    rmsnorm_kernel<<<N_, tb, 0, stream>>>(hbuf, fnw, xn);   // xn = xf now
    gating_kernel<<<N_ / 4, tb, 0, stream>>>(hbuf, gw, fnw, top_idx, top_w);
    route_kernel<<<1, 1024, 0, stream>>>(top_idx, offs, token_list, tok_pos);

    // experts (routed top-2 + shared as slot 8): h1 = silu(xg@w1)*(xg@w3); eo = h1@w2
    gemm_bt<3, 1><<<dim3(16, 32, 9), tb512, 0, stream>>>(xn, ew13_t, qkv, nullptr,
        0, 1024, 1024, 1024, 1024, 2097152, token_list, offs, nullptr, nullptr, nullptr);  // qkv = h1
    // eo with SPLIT-K=2 (z = e*2+kh): partial-0 -> eo, partial-1 -> eo2 (= dead ew13_t)
    gemm_bt<0, 3><<<dim3(8, 32, 18), tb512, 0, stream>>>((const bf16*)qkv, ew2_t, eo, nullptr,
        0, 512, 1024, 1024, 1024, 1048576, nullptr, offs, nullptr, nullptr, eo2);

    combine_kernel<<<4096, tb, 0, stream>>>(hbuf, eo, eo2, tok_pos, top_w, (float*)d_out);
}

// Round 18
// 356.637 us; speedup vs baseline: 1.0001x; 1.0001x over previous
//
#include <hip/hip_runtime.h>
#include <hip/hip_bf16.h>
#include <stdint.h>

// Transformer block for MI355X (gfx950).
// B=2 S=2048 D=1024 H=16 HD=64 E=8 K=2 HM=HS=1024, fp32 in/out, bf16 MFMA compute.
// Base: R10 proven GEMM config (353 us). This round: attn Q-block 128->64
// (wave owns 16 q-rows) to lift attn occupancy 2->4 blocks/CU. Split-K reverted (neutral).

typedef __hip_bfloat16 bf16;
typedef __attribute__((ext_vector_type(8))) __bf16 bf16x8;
typedef __attribute__((ext_vector_type(4))) float f32x4;
typedef __attribute__((ext_vector_type(16))) float f32x16;
typedef __attribute__((ext_vector_type(2))) unsigned int u32x2;

#define S_  2048
#define D_  1024
#define N_  4096      // B*S

__device__ __forceinline__ float b2f(bf16 h) { return __bfloat162float(h); }
__device__ __forceinline__ bf16  f2b(float f) { return __float2bfloat16(f); }

__device__ __forceinline__ bf16x8 ld_bf16x8(const bf16* p) {
    union { uint4 u; bf16x8 v; } x;
    x.u = *(const uint4*)p;
    return x.v;
}

__device__ __forceinline__ void gload_lds16(const void* gsrc, void* ldst) {
    __builtin_amdgcn_global_load_lds(
        (__attribute__((address_space(1))) void*)const_cast<void*>(gsrc),
        (__attribute__((address_space(3))) void*)ldst, 16, 0, 0);
}

// gfx950 LDS transpose read (per-lane addr = base + 8*lane).
__device__ __forceinline__ u32x2 tr16_read(unsigned lds_off) {
    u32x2 d;
    asm volatile("ds_read_b64_tr_b16 %0, %1" : "=v"(d) : "v"(lds_off));
    return d;
}

// granule swizzle for [row][32] bf16 LDS tiles (64B rows, 4x16B granules).
__device__ __forceinline__ int swz4(int r) { return ((r >> 1) ^ (r >> 3)) & 3; }

// ---------------------------------------------------------------------------
// All weight transposes (fp32 -> bf16) in ONE launch. grid (16,16,31).
// ---------------------------------------------------------------------------
__global__ __launch_bounds__(256)
void transpose_all(const float* __restrict__ wq, const float* __restrict__ wk,
                   const float* __restrict__ wv, const float* __restrict__ wo,
                   const float* __restrict__ ew1, const float* __restrict__ ew2,
                   const float* __restrict__ ew3, const float* __restrict__ sw1,
                   const float* __restrict__ sw2, const float* __restrict__ sw3,
                   bf16* __restrict__ wqkv_t, bf16* __restrict__ wo_t,
                   bf16* __restrict__ ew13_t, bf16* __restrict__ ew2_t)
{
    __shared__ float t[64][65];
    const int z = blockIdx.z;
    const float* in; bf16* out; int rm = 1, ro = 0;
    if (z < 3)        { in = (z == 0 ? wq : z == 1 ? wk : wv); out = wqkv_t + (size_t)z * 1048576; }
    else if (z == 3)  { in = wo; out = wo_t; }
    else if (z < 12)  { const int e = z - 4;  in = ew1 + (size_t)e * 1048576; out = ew13_t + (size_t)e * 2097152; rm = 2; ro = 0; }
    else if (z < 20)  { const int e = z - 12; in = ew3 + (size_t)e * 1048576; out = ew13_t + (size_t)e * 2097152; rm = 2; ro = 1; }
    else if (z < 28)  { const int e = z - 20; in = ew2 + (size_t)e * 1048576; out = ew2_t + (size_t)e * 1048576; }
    else if (z == 28) { in = sw1; out = ew13_t + (size_t)8 * 2097152; rm = 2; ro = 0; }
    else if (z == 29) { in = sw3; out = ew13_t + (size_t)8 * 2097152; rm = 2; ro = 1; }
    else              { in = sw2; out = ew2_t + (size_t)8 * 1048576; }

    const int c0 = blockIdx.x * 64, r0 = blockIdx.y * 64;
    const int tx = (threadIdx.x & 15) * 4, ty = threadIdx.x >> 4;   // ty 0..15
#pragma unroll
    for (int i = 0; i < 4; i++)
        *(float4*)&t[ty + i * 16][tx] = *(const float4*)(in + (size_t)(r0 + ty + i * 16) * 1024 + c0 + tx);
    __syncthreads();
#pragma unroll
    for (int i = 0; i < 4; i++) {
        const int lc = ty + i * 16;
        union { bf16 h[4]; uint2 u; } pk;
#pragma unroll
        for (int j = 0; j < 4; j++) pk.h[j] = f2b(t[tx + j][lc]);
        *(uint2*)&out[(size_t)((c0 + lc) * rm + ro) * 1024 + r0 + tx] = pk.u;
    }
}

// ---------------------------------------------------------------------------
// RMSNorm: fp32 in -> bf16 out.  grid N_, block 256
// ---------------------------------------------------------------------------
__global__ __launch_bounds__(256)
void rmsnorm_kernel(const float* __restrict__ x, const float* __restrict__ w,
                    bf16* __restrict__ out)
{
    const int n = blockIdx.x;
    const int tid = threadIdx.x;
    const float4 v = *(const float4*)(x + (size_t)n * D_ + tid * 4);
    float ss = v.x * v.x + v.y * v.y + v.z * v.z + v.w * v.w;
#pragma unroll
    for (int m = 1; m < 64; m <<= 1) ss += __shfl_xor(ss, m);
    __shared__ float red[4];
    if ((tid & 63) == 0) red[tid >> 6] = ss;
    __syncthreads();
    const float tot = red[0] + red[1] + red[2] + red[3];
    const float rstd = rsqrtf(tot * (1.0f / D_) + 1e-6f);
    const float4 wv = *(const float4*)(w + tid * 4);
    union { bf16 h[4]; uint2 u; } pk;
    pk.h[0] = f2b(v.x * rstd * wv.x);
    pk.h[1] = f2b(v.y * rstd * wv.y);
    pk.h[2] = f2b(v.z * rstd * wv.z);
    pk.h[3] = f2b(v.w * rstd * wv.w);
    *(uint2*)(out + (size_t)n * D_ + tid * 4) = pk.u;
}

// ---------------------------------------------------------------------------
// GEMM: C[M][N] = A[M][K] * Bt[N][K]^T  (A,Bt bf16 row-major; acc fp32)
// 128x128 tile, BK=32, 512 threads = 8 waves (2Mx4N), 64x32/wave.
// PROVEN 353us config (R10): acc = 2x f32x16 = 32 regs; LDS 32 KB.
// Counted-vmcnt depth-1: issue next tile (1 A + 1 B gload/thread), vmcnt(2),
// s_barrier, compute (4x mfma_32x32x16), s_barrier. Source-granule swz4.
// C layout (m74/m101): row=(i&3)+8*(i>>2)+4*(lane>>5), col=lane&31.
// XCD swizzle ONLY for MODE==0 (grouped early-exit + swizzle = R4/R5 bug).
// EPI: 0 = store bf16, 1 = store fp32, 2 = fp32 resid add,
//      3 = swiglu pair -> bf16, 4 = fused RoPE (qkv layout, ldc=3072)
// MODE: 0 = plain, 1 = grouped+gathered A rows (token_list), 2 = grouped contiguous
// ---------------------------------------------------------------------------
template<int EPI, int MODE>
__global__ __launch_bounds__(512)
void gemm_bt(const bf16* __restrict__ A, const bf16* __restrict__ Bt,
             void* __restrict__ Cout, const float* __restrict__ resid,
             int M, int Kdim, int lda, int ldb, int ldc, long bstride,
             const int* __restrict__ tlist, const int* __restrict__ offs,
             const float* __restrict__ fc, const float* __restrict__ fs)
{
    __shared__ bf16 As[2][128 * 32];
    __shared__ bf16 Bs[2][128 * 32];
    const int tid = threadIdx.x;
    const int wave = tid >> 6, lane = tid & 63;

    int bx, by;
    if constexpr (MODE == 0) {
        const int gx = gridDim.x;
        const int nwg = gx * gridDim.y;
        int flat = blockIdx.y * gx + blockIdx.x;
        flat = (flat & 7) * (nwg >> 3) + (flat >> 3);
        bx = flat % gx; by = flat / gx;
    } else {
        bx = blockIdx.x; by = blockIdx.y;
    }

    int mcount = M, outBase = 0;
    const bf16* Bp = Bt;
    if (MODE != 0) {
        const int e = blockIdx.z;
        outBase = offs[e];
        mcount = offs[e + 1] - outBase;
        Bp = Bt + (size_t)e * bstride;
    }
    const int m0 = by * 128;
    if (m0 >= mcount) return;
    const int n0 = bx * 128;

    // staging: 1 A-load + 1 B-load per thread. row = tid>>2 (0..127),
    // LDS slot granule = tid&3; SOURCE granule pre-swizzled (slot^swz4(row)).
    const int srow = tid >> 2;
    const int sc4 = tid & 3;
    const int scol = (sc4 ^ swz4(srow)) * 8;
    int rA = m0 + srow;
    if (rA >= mcount) rA = mcount - 1;
    long arow;
    if (MODE == 1)      arow = tlist[outBase + rA];
    else if (MODE == 2) arow = (long)outBase + rA;
    else                arow = rA;
    const bf16* aptr = A + (size_t)arow * lda + scol;
    const bf16* bptr = Bp + (size_t)(n0 + srow) * ldb + scol;

    f32x16 acc[2];
#pragma unroll
    for (int tm = 0; tm < 2; tm++)
#pragma unroll
        for (int i = 0; i < 16; i++) acc[tm][i] = 0.f;

    const int wm = (wave >> 2) * 64, wn = (wave & 3) * 32;
    const int l31 = lane & 31, l5 = lane >> 5;

    // fragment LDS element offsets (slot = granule ^ swz4(row))
    int aoff[2][2], boff[2];
#pragma unroll
    for (int tm = 0; tm < 2; tm++) {
        const int ra = wm + tm * 32 + l31;
#pragma unroll
        for (int kk = 0; kk < 2; kk++)
            aoff[tm][kk] = ra * 32 + ((kk * 2 + l5) ^ swz4(ra)) * 8;
    }
    {
        const int rb = wn + l31;
#pragma unroll
        for (int kk = 0; kk < 2; kk++)
            boff[kk] = rb * 32 + ((kk * 2 + l5) ^ swz4(rb)) * 8;
    }

    const int nkt = Kdim >> 5;
    // prologue: stage tile 0 into buffer 0
    gload_lds16(aptr, (char*)&As[0][0] + wave * 1024);
    gload_lds16(bptr, (char*)&Bs[0][0] + wave * 1024);

    int p = 0;
    for (int kt = 0; kt < nkt; kt++) {
        if (kt + 1 < nkt) {
            const int ko = (kt + 1) << 5;
            gload_lds16(aptr + ko, (char*)&As[p ^ 1][0] + wave * 1024);
            gload_lds16(bptr + ko, (char*)&Bs[p ^ 1][0] + wave * 1024);
            asm volatile("s_waitcnt vmcnt(2)" ::: "memory");   // FIFO: current buffer landed
        } else {
            asm volatile("s_waitcnt vmcnt(0)" ::: "memory");
        }
        asm volatile("s_barrier" ::: "memory");

        const bf16* Ab = &As[p][0];
        const bf16* Bb = &Bs[p][0];
#pragma unroll
        for (int kk = 0; kk < 2; kk++) {
            const bf16x8 bf0 = ld_bf16x8(&Bb[boff[kk]]);
            const bf16x8 af0 = ld_bf16x8(&Ab[aoff[0][kk]]);
            const bf16x8 af1 = ld_bf16x8(&Ab[aoff[1][kk]]);
            acc[0] = __builtin_amdgcn_mfma_f32_32x32x16_bf16(af0, bf0, acc[0], 0, 0, 0);
            acc[1] = __builtin_amdgcn_mfma_f32_32x32x16_bf16(af1, bf0, acc[1], 0, 0, 0);
        }

        asm volatile("s_barrier" ::: "memory");
        p ^= 1;
    }

    // epilogue: row = (i&3) + 8*(i>>2) + 4*l5, col = l31 within each 32x32 tile
#pragma unroll
    for (int tm = 0; tm < 2; tm++)
#pragma unroll
        for (int i = 0; i < 16; i++) {
            const int r = m0 + wm + tm * 32 + (i & 3) + 8 * (i >> 2) + 4 * l5;
            const int c = n0 + wn + l31;
            const float v = acc[tm][i];
            if (EPI == 3) {
                const float other = __shfl_xor(v, 1);
                const float res = (v / (1.f + __expf(-v))) * other;  // silu(g1)*g3 on even lanes
                if (((lane & 1) == 0) && r < mcount)
                    ((bf16*)Cout)[(size_t)(outBase + r) * ldc + (c >> 1)] = f2b(res);
            } else if (EPI == 4) {
                // fused RoPE: c<1024 q (scale 1/8), c<2048 k, else v passthrough
                const float other = __shfl_xor(v, 1);
                float o = v;
                if (c < 2048) {
                    const int s = r & (S_ - 1);
                    const int jf = (c & 63) >> 1;
                    const float co = fc[s * 32 + jf], si = fs[s * 32 + jf];
                    o = v * co + other * ((c & 1) ? si : -si);
                    if (c < 1024) o *= 0.125f;   // fold 1/sqrt(HD) into q
                }
                ((bf16*)Cout)[(size_t)r * ldc + c] = f2b(o);
            } else if (r < mcount) {
                const size_t oi = (size_t)(outBase + r) * ldc + c;
                if (EPI == 0)      ((bf16*)Cout)[oi] = f2b(v);
                else if (EPI == 1) ((float*)Cout)[oi] = v;
                else               ((float*)Cout)[oi] = resid[oi] + v;
            }
        }
}

// ---------------------------------------------------------------------------
// Flash attention, non-causal, swapped-operand structure.
// grid (S/64, H=16, B=2) = 1024 blocks (4/CU, was 2/CU), block 256
// (4 waves, *** 16 q-rows/wave ***). KV tile = 64. Occupancy fix: attn was
// wave-starved at 8 waves/CU; this doubles resident waves with identical
// per-wave structure (qb dimension removed).
// ---------------------------------------------------------------------------
__global__ __launch_bounds__(256)
void attn_kernel(const bf16* __restrict__ qkv, bf16* __restrict__ out)
{
    __shared__ __align__(16) bf16 Ks[64 * 72];          // [kv][64 hd] pad 72
    __shared__ __align__(16) bf16 Vs[4 * 1032 + 8];     // [hd chunk][64 kv][16 hd], chunk stride 1032
    const int tid = threadIdx.x, wave = tid >> 6, lane = tid & 63;
    const int b = blockIdx.z, hh = blockIdx.y;
    const int q0 = blockIdx.x * 64;
    const bf16* base  = qkv + ((size_t)b * S_) * 3072 + (size_t)hh * 64;
    const bf16* kbase = base + 1024;
    const bf16* vbase = base + 2048;
    const int fr = lane & 15, fg = lane >> 4;

    // Q fragments (B-operand): lane holds q = fr, hd = fg*8.. (+32 per s2)
    bf16x8 aq[2];
#pragma unroll
    for (int s2 = 0; s2 < 2; s2++)
        aq[s2] = ld_bf16x8(base + (size_t)(q0 + wave * 16 + fr) * 3072 + s2 * 32 + fg * 8);

    f32x4 zero4 = {0.f, 0.f, 0.f, 0.f};
    f32x4 acc_o[4];          // [hf]: rows q = fg*4+j, cols hd = hf*16+fr
    float mrow = -1e30f, lrow = 0.f;   // per-lane stats for q = fr
#pragma unroll
    for (int hf = 0; hf < 4; hf++) acc_o[hf] = zero4;

    const int srow = tid >> 2, sc4 = tid & 3;
    const unsigned vtr0 =
        (unsigned)(uintptr_t)(__attribute__((address_space(3))) void*)&Vs[0] + lane * 8;

    // register-staged K/V prefetch (double-buffered against compute)
    uint4 kg0, kg1, vg0, vg1;
    {
        const bf16* kr = kbase + (size_t)srow * 3072 + sc4 * 16;
        kg0 = *(const uint4*)kr; kg1 = *(const uint4*)(kr + 8);
        const bf16* vr = vbase + (size_t)srow * 3072 + sc4 * 16;
        vg0 = *(const uint4*)vr; vg1 = *(const uint4*)(vr + 8);
    }

    for (int kv0 = 0; kv0 < S_; kv0 += 64) {
        __syncthreads();
        *(uint4*)&Ks[srow * 72 + sc4 * 16]         = kg0;
        *(uint4*)&Ks[srow * 72 + sc4 * 16 + 8]     = kg1;
        *(uint4*)&Vs[sc4 * 1032 + srow * 16]       = vg0;
        *(uint4*)&Vs[sc4 * 1032 + srow * 16 + 8]   = vg1;
        __syncthreads();
        if (kv0 + 64 < S_) {    // prefetch next tile (hides HBM under compute)
            const bf16* kr = kbase + (size_t)(kv0 + 64 + srow) * 3072 + sc4 * 16;
            kg0 = *(const uint4*)kr; kg1 = *(const uint4*)(kr + 8);
            const bf16* vr = vbase + (size_t)(kv0 + 64 + srow) * 3072 + sc4 * 16;
            vg0 = *(const uint4*)vr; vg1 = *(const uint4*)(vr + 8);
        }

        // ---- QK^T (swapped): sc[kt] = K_tile(kt) x Q, S^T layout ----
        f32x4 sc[4];
#pragma unroll
        for (int kt = 0; kt < 4; kt++) sc[kt] = zero4;
        __builtin_amdgcn_s_setprio(1);
#pragma unroll
        for (int kt = 0; kt < 4; kt++) {
            const bf16x8 k0 = ld_bf16x8(&Ks[(kt * 16 + fr) * 72 + fg * 8]);
            const bf16x8 k1 = ld_bf16x8(&Ks[(kt * 16 + fr) * 72 + 32 + fg * 8]);
            sc[kt] = __builtin_amdgcn_mfma_f32_16x16x32_bf16(k0, aq[0], sc[kt], 0, 0, 0);
            sc[kt] = __builtin_amdgcn_mfma_f32_16x16x32_bf16(k1, aq[1], sc[kt], 0, 0, 0);
        }
        __builtin_amdgcn_s_setprio(0);

        // ---- online softmax, fully in-register (lane owns row q = fr) ----
        bf16x8 pcomb[2];   // [tp]: A-operand P fragments (two 16-kv tiles packed)
        float scalv;
        {
            float pm = -1e30f;
#pragma unroll
            for (int kt = 0; kt < 4; kt++)
#pragma unroll
                for (int j = 0; j < 4; j++) pm = fmaxf(pm, sc[kt][j]);
            pm = fmaxf(pm, __shfl_xor(pm, 16));
            pm = fmaxf(pm, __shfl_xor(pm, 32));
            const float mnew = fmaxf(mrow, pm);
            const float scal = __expf(mrow - mnew);
            mrow = mnew;
            float ps = 0.f;
            union { bf16 h[16]; bf16x8 v8[2]; } pk;
#pragma unroll
            for (int kt = 0; kt < 4; kt++)
#pragma unroll
                for (int j = 0; j < 4; j++) {
                    const float p = __expf(sc[kt][j] - mnew);
                    ps += p;
                    pk.h[kt * 4 + j] = f2b(p);
                }
            pcomb[0] = pk.v8[0];
            pcomb[1] = pk.v8[1];
            ps += __shfl_xor(ps, 16);
            ps += __shfl_xor(ps, 32);
            lrow = lrow * scal + ps;
            scalv = scal;
        }

        // rescale O (its rows are q = fg*4+j -> fetch that q's scal)
#pragma unroll
        for (int j = 0; j < 4; j++) {
            const int src = (lane & 48) + fg * 4 + j;
            const float s0 = __shfl(scalv, src);
#pragma unroll
            for (int hf = 0; hf < 4; hf++)
                acc_o[hf][j] *= s0;
        }

        // ---- PV: B-operand via hw transpose-read, two 16-kv tiles per mfma ----
#pragma unroll
        for (int tp = 0; tp < 2; tp++) {
            union { u32x2 d2[2]; bf16x8 v8; } vc[4];
#pragma unroll
            for (int hf = 0; hf < 4; hf++) {
                vc[hf].d2[0] = tr16_read(vtr0 + hf * 2064 + (tp * 2)     * 512);
                vc[hf].d2[1] = tr16_read(vtr0 + hf * 2064 + (tp * 2 + 1) * 512);
            }
            asm volatile("s_waitcnt lgkmcnt(0)" ::: "memory");
            __builtin_amdgcn_sched_barrier(0);   // rule 18: keep MFMAs below the wait
            __builtin_amdgcn_s_setprio(1);
#pragma unroll
            for (int hf = 0; hf < 4; hf++)
                acc_o[hf] = __builtin_amdgcn_mfma_f32_16x16x32_bf16(
                    pcomb[tp], vc[hf].v8, acc_o[hf], 0, 0, 0);
            __builtin_amdgcn_s_setprio(0);
        }
    }

    // ---- epilogue: out rows q = fg*4+j, cols hd = hf*16+fr ----
    {
        const float inv = 1.f / lrow;
#pragma unroll
        for (int j = 0; j < 4; j++) {
            const float ij = __shfl(inv, (lane & 48) + fg * 4 + j);
            const int r = q0 + wave * 16 + fg * 4 + j;
#pragma unroll
            for (int hf = 0; hf < 4; hf++)
                out[((size_t)(b * S_ + r)) * D_ + hh * 64 + hf * 16 + fr] =
                    f2b(acc_o[hf][j] * ij);
        }
    }
}

// ---------------------------------------------------------------------------
// MoE gating: fp32 scores from pre-norm h (recompute rmsnorm scale), top-2.
// ---------------------------------------------------------------------------
__global__ __launch_bounds__(256)
void gating_kernel(const float* __restrict__ h, const float* __restrict__ gw,
                   const float* __restrict__ wnorm,
                   int* __restrict__ top_idx, float* __restrict__ top_w)
{
    const int wave = threadIdx.x >> 6, lane = threadIdx.x & 63;
    const int n = blockIdx.x * 4 + wave;
    const float* hr = h + (size_t)n * D_;
    float acc[8] = {0.f, 0.f, 0.f, 0.f, 0.f, 0.f, 0.f, 0.f};
    float ss = 0.f;
    for (int d = lane * 4; d < D_; d += 256) {
        const float4 hv = *(const float4*)(hr + d);
        const float4 wv = *(const float4*)(wnorm + d);
        ss += hv.x * hv.x + hv.y * hv.y + hv.z * hv.z + hv.w * hv.w;
        const float x0 = hv.x * wv.x, x1 = hv.y * wv.y, x2 = hv.z * wv.z, x3 = hv.w * wv.w;
#pragma unroll
        for (int e2 = 0; e2 < 8; e2++) {
            const float4 gv = *(const float4*)(gw + e2 * D_ + d);
            acc[e2] += x0 * gv.x + x1 * gv.y + x2 * gv.z + x3 * gv.w;
        }
    }
#pragma unroll
    for (int m = 1; m < 64; m <<= 1) {
        ss += __shfl_xor(ss, m);
#pragma unroll
        for (int e2 = 0; e2 < 8; e2++) acc[e2] += __shfl_xor(acc[e2], m);
    }
    if (lane == 0) {
        const float rstd = rsqrtf(ss * (1.0f / D_) + 1e-6f);
        float s[8];
#pragma unroll
        for (int e2 = 0; e2 < 8; e2++) s[e2] = acc[e2] * rstd;
        int e0 = 0;
#pragma unroll
        for (int e2 = 1; e2 < 8; e2++) if (s[e2] > s[e0]) e0 = e2;
        int e1 = (e0 == 0) ? 1 : 0;
#pragma unroll
        for (int e2 = 0; e2 < 8; e2++) if (e2 != e0 && s[e2] > s[e1]) e1 = e2;
        const float mx = s[e0];
        float Z = 0.f;
        float p[8];
#pragma unroll
        for (int e2 = 0; e2 < 8; e2++) { p[e2] = __expf(s[e2] - mx); Z += p[e2]; }
        const float v0 = p[e0] / Z, v1 = p[e1] / Z;
        const float sm = v0 + v1 + 1e-9f;
        top_idx[n * 2] = e0; top_idx[n * 2 + 1] = e1;
        top_w[n * 2] = v0 / sm; top_w[n * 2 + 1] = v1 / sm;
    }
}

// ---------------------------------------------------------------------------
// Routing: single block, LDS atomics only. histogram -> offsets -> scatter.
// Adds the shared expert as slot 8: identity token list for all 4096 tokens.
// ---------------------------------------------------------------------------
__global__ __launch_bounds__(1024)
void route_kernel(const int* __restrict__ top_idx, int* __restrict__ offs,
                  int* __restrict__ token_list, int* __restrict__ tok_pos)
{
    __shared__ int hist[8];
    __shared__ int base[8];
    const int tid = threadIdx.x;
    if (tid < 8) hist[tid] = 0;
    __syncthreads();
    int4 e4a = *(const int4*)(top_idx + tid * 8);
    int4 e4b = *(const int4*)(top_idx + tid * 8 + 4);
    int myidx[8] = {e4a.x, e4a.y, e4a.z, e4a.w, e4b.x, e4b.y, e4b.z, e4b.w};
#pragma unroll
    for (int i = 0; i < 8; i++) atomicAdd(&hist[myidx[i]], 1);
    __syncthreads();
    if (tid == 0) {
        int o = 0;
#pragma unroll
        for (int e = 0; e < 8; e++) { base[e] = o; offs[e] = o; o += hist[e]; }
        offs[8] = o;          // == 8192 always
        offs[9] = o + N_;     // shared-expert segment
    }
    __syncthreads();
    if (tid < 8) hist[tid] = 0;
    __syncthreads();
#pragma unroll
    for (int i = 0; i < 8; i++) {
        const int entry = tid * 8 + i;
        const int e = myidx[i];
        const int pos = base[e] + atomicAdd(&hist[e], 1);
        token_list[pos] = entry >> 1;
        tok_pos[entry] = pos;
    }
    // shared expert (slot 8): identity gather over all tokens
#pragma unroll
    for (int i = 0; i < 4; i++)
        token_list[2 * N_ + tid * 4 + i] = tid * 4 + i;
}

// out = h + eo[shared(n)] + w0*eo[pos0] + w1*eo[pos1]
__global__ __launch_bounds__(256)
void combine_kernel(const float* __restrict__ h, const bf16* __restrict__ eo,
                    const int* __restrict__ tok_pos, const float* __restrict__ top_w,
                    float* __restrict__ out)
{
    const int idx = blockIdx.x * 256 + threadIdx.x;   // N_*D_/4 total
    const int n = idx >> 8;
    const int c = (idx & 255) * 4;
    const float4 hv = *(const float4*)(h + (size_t)n * D_ + c);
    const int p0 = tok_pos[n * 2], p1 = tok_pos[n * 2 + 1];
    const float w0 = top_w[n * 2], w1 = top_w[n * 2 + 1];
    union { uint2 u; bf16 hh[4]; } a0, a1, ash;
    a0.u  = *(const uint2*)(eo + (size_t)p0 * D_ + c);
    a1.u  = *(const uint2*)(eo + (size_t)p1 * D_ + c);
    ash.u = *(const uint2*)(eo + (size_t)(2 * N_ + n) * D_ + c);
    float4 r;
    r.x = hv.x + b2f(ash.hh[0]) + w0 * b2f(a0.hh[0]) + w1 * b2f(a1.hh[0]);
    r.y = hv.y + b2f(ash.hh[1]) + w0 * b2f(a0.hh[1]) + w1 * b2f(a1.hh[1]);
    r.z = hv.z + b2f(ash.hh[2]) + w0 * b2f(a0.hh[2]) + w1 * b2f(a1.hh[2]);
    r.w = hv.w + b2f(ash.hh[3]) + w0 * b2f(a0.hh[3]) + w1 * b2f(a1.hh[3]);
    *(float4*)(out + (size_t)n * D_ + c) = r;
}

// ---------------------------------------------------------------------------
extern "C" void kernel_launch(void* const* d_in, const int* in_sizes, int n_in,
                              void* d_out, int out_size, void* d_ws, size_t ws_size,
                              hipStream_t stream)
{
    const float* x   = (const float*)d_in[0];
    const float* fc  = (const float*)d_in[1];
    const float* fs  = (const float*)d_in[2];
    const float* anw = (const float*)d_in[3];
    const float* fnw = (const float*)d_in[4];
    const float* wq  = (const float*)d_in[5];
    const float* wk  = (const float*)d_in[6];
    const float* wv  = (const float*)d_in[7];
    const float* wo  = (const float*)d_in[8];
    const float* gw  = (const float*)d_in[9];
    const float* ew1 = (const float*)d_in[10];
    const float* ew2 = (const float*)d_in[11];
    const float* ew3 = (const float*)d_in[12];
    const float* sw1 = (const float*)d_in[13];
    const float* sw2 = (const float*)d_in[14];
    const float* sw3 = (const float*)d_in[15];

    char* ws = (char*)d_ws;
    bf16*  wqkv_t = (bf16*)(ws + 0);           //  6291456 B  [3072][1024]
    bf16*  wo_t   = (bf16*)(ws + 6291456);     //  2097152 B  [1024][1024]
    bf16*  ew13_t = (bf16*)(ws + 8388608);     // 37748736 B  9 x [2048][1024] interleaved (slot 8 = shared sw1/sw3)
    bf16*  ew2_t  = (bf16*)(ws + 46137344);    // 18874368 B  9 x [1024][1024] (slot 8 = shared sw2)
    bf16*  xn     = (bf16*)(ws + 65011712);    //  8388608 B  [4096][1024]  (reused as xf)
    bf16*  qkv    = (bf16*)(ws + 73400320);    // 25165824 B  [4096][3072]  (reused as h1 [12288][1024])
    bf16*  attn   = (bf16*)(ws + 98566144);    //  8388608 B  [4096][1024]
    float* hbuf   = (float*)(ws + 106954752);  // 16777216 B  [4096][1024]
    bf16*  eo     = (bf16*)(ws + 123731968);   // 25165824 B  [12288][1024]
    char*  misc   = ws + 148897792;
    int*   offs       = (int*)(misc + 0);              // 16 ints
    int*   top_idx    = (int*)(misc + 128);            // 8192 ints
    float* top_w      = (float*)(misc + 128 + 32768);  // 8192 floats
    int*   token_list = (int*)(misc + 128 + 65536);    // 12288 ints
    int*   tok_pos    = (int*)(misc + 128 + 131072);   // 8192 ints

    const dim3 tb(256);
    const dim3 tb512(512);
    // all weight transposes in one launch (64x64 tiles)
    transpose_all<<<dim3(16, 16, 31), tb, 0, stream>>>(
        wq, wk, wv, wo, ew1, ew2, ew3, sw1, sw2, sw3,
        wqkv_t, wo_t, ew13_t, ew2_t);

    // attention branch (RoPE fused into QKV epilogue)
    rmsnorm_kernel<<<N_, tb, 0, stream>>>(x, anw, xn);
    gemm_bt<4, 0><<<dim3(24, 32, 1), tb512, 0, stream>>>(xn, wqkv_t, qkv, nullptr,
        N_, 1024, 1024, 1024, 3072, 0, nullptr, nullptr, fc, fs);
    attn_kernel<<<dim3(32, 16, 2), tb, 0, stream>>>(qkv, attn);
    gemm_bt<2, 0><<<dim3(8, 32, 1), tb512, 0, stream>>>(attn, wo_t, hbuf, x,
        N_, 1024, 1024, 1024, 1024, 0, nullptr, nullptr, nullptr, nullptr);

    // FFN branch
    rmsnorm_kernel<<<N_, tb, 0, stream>>>(hbuf, fnw, xn);   // xn = xf now
    gating_kernel<<<N_ / 4, tb, 0, stream>>>(hbuf, gw, fnw, top_idx, top_w);
    route_kernel<<<1, 1024, 0, stream>>>(top_idx, offs, token_list, tok_pos);

    // experts (routed top-2 + shared as slot 8): h1 = silu(xg@w1)*(xg@w3); eo = h1@w2
    gemm_bt<3, 1><<<dim3(16, 32, 9), tb512, 0, stream>>>(xn, ew13_t, qkv, nullptr,
        0, 1024, 1024, 1024, 1024, 2097152, token_list, offs, nullptr, nullptr);   // qkv = h1 now
    gemm_bt<0, 2><<<dim3(8, 32, 9), tb512, 0, stream>>>((const bf16*)qkv, ew2_t, eo, nullptr,
        0, 1024, 1024, 1024, 1024, 1048576, nullptr, offs, nullptr, nullptr);

    combine_kernel<<<4096, tb, 0, stream>>>(hbuf, eo, tok_pos, top_w, (float*)d_out);
}

// Round 19
// 342.214 us; speedup vs baseline: 1.0423x; 1.0421x over previous
//
#include <hip/hip_runtime.h>
#include <hip/hip_bf16.h>
#include <stdint.h>

// Transformer block for MI355X (gfx950).
// B=2 S=2048 D=1024 H=16 HD=64 E=8 K=2 HM=HS=1024, fp32 in/out, bf16 MFMA compute.
// Final config: R10-proven GEMM/attn structure (353-354 us measured) +
// rmsnorm#2 fused into gating_kernel (one fewer pass over hbuf).

typedef __hip_bfloat16 bf16;
typedef __attribute__((ext_vector_type(8))) __bf16 bf16x8;
typedef __attribute__((ext_vector_type(4))) float f32x4;
typedef __attribute__((ext_vector_type(16))) float f32x16;
typedef __attribute__((ext_vector_type(2))) unsigned int u32x2;

#define S_  2048
#define D_  1024
#define N_  4096      // B*S

__device__ __forceinline__ float b2f(bf16 h) { return __bfloat162float(h); }
__device__ __forceinline__ bf16  f2b(float f) { return __float2bfloat16(f); }

__device__ __forceinline__ bf16x8 ld_bf16x8(const bf16* p) {
    union { uint4 u; bf16x8 v; } x;
    x.u = *(const uint4*)p;
    return x.v;
}

__device__ __forceinline__ void gload_lds16(const void* gsrc, void* ldst) {
    __builtin_amdgcn_global_load_lds(
        (__attribute__((address_space(1))) void*)const_cast<void*>(gsrc),
        (__attribute__((address_space(3))) void*)ldst, 16, 0, 0);
}

// gfx950 LDS transpose read (per-lane addr = base + 8*lane).
__device__ __forceinline__ u32x2 tr16_read(unsigned lds_off) {
    u32x2 d;
    asm volatile("ds_read_b64_tr_b16 %0, %1" : "=v"(d) : "v"(lds_off));
    return d;
}

// granule swizzle for [row][32] bf16 LDS tiles (64B rows, 4x16B granules).
__device__ __forceinline__ int swz4(int r) { return ((r >> 1) ^ (r >> 3)) & 3; }

// ---------------------------------------------------------------------------
// All weight transposes (fp32 -> bf16) in ONE launch. grid (16,16,31).
// 64x64 tiles, float4 reads, 8B packed bf16 writes.
// ---------------------------------------------------------------------------
__global__ __launch_bounds__(256)
void transpose_all(const float* __restrict__ wq, const float* __restrict__ wk,
                   const float* __restrict__ wv, const float* __restrict__ wo,
                   const float* __restrict__ ew1, const float* __restrict__ ew2,
                   const float* __restrict__ ew3, const float* __restrict__ sw1,
                   const float* __restrict__ sw2, const float* __restrict__ sw3,
                   bf16* __restrict__ wqkv_t, bf16* __restrict__ wo_t,
                   bf16* __restrict__ ew13_t, bf16* __restrict__ ew2_t)
{
    __shared__ float t[64][65];
    const int z = blockIdx.z;
    const float* in; bf16* out; int rm = 1, ro = 0;
    if (z < 3)        { in = (z == 0 ? wq : z == 1 ? wk : wv); out = wqkv_t + (size_t)z * 1048576; }
    else if (z == 3)  { in = wo; out = wo_t; }
    else if (z < 12)  { const int e = z - 4;  in = ew1 + (size_t)e * 1048576; out = ew13_t + (size_t)e * 2097152; rm = 2; ro = 0; }
    else if (z < 20)  { const int e = z - 12; in = ew3 + (size_t)e * 1048576; out = ew13_t + (size_t)e * 2097152; rm = 2; ro = 1; }
    else if (z < 28)  { const int e = z - 20; in = ew2 + (size_t)e * 1048576; out = ew2_t + (size_t)e * 1048576; }
    else if (z == 28) { in = sw1; out = ew13_t + (size_t)8 * 2097152; rm = 2; ro = 0; }
    else if (z == 29) { in = sw3; out = ew13_t + (size_t)8 * 2097152; rm = 2; ro = 1; }
    else              { in = sw2; out = ew2_t + (size_t)8 * 1048576; }

    const int c0 = blockIdx.x * 64, r0 = blockIdx.y * 64;
    const int tx = (threadIdx.x & 15) * 4, ty = threadIdx.x >> 4;   // ty 0..15
#pragma unroll
    for (int i = 0; i < 4; i++)
        *(float4*)&t[ty + i * 16][tx] = *(const float4*)(in + (size_t)(r0 + ty + i * 16) * 1024 + c0 + tx);
    __syncthreads();
#pragma unroll
    for (int i = 0; i < 4; i++) {
        const int lc = ty + i * 16;
        union { bf16 h[4]; uint2 u; } pk;
#pragma unroll
        for (int j = 0; j < 4; j++) pk.h[j] = f2b(t[tx + j][lc]);
        *(uint2*)&out[(size_t)((c0 + lc) * rm + ro) * 1024 + r0 + tx] = pk.u;
    }
}

// ---------------------------------------------------------------------------
// RMSNorm: fp32 in -> bf16 out.  grid N_, block 256
// ---------------------------------------------------------------------------
__global__ __launch_bounds__(256)
void rmsnorm_kernel(const float* __restrict__ x, const float* __restrict__ w,
                    bf16* __restrict__ out)
{
    const int n = blockIdx.x;
    const int tid = threadIdx.x;
    const float4 v = *(const float4*)(x + (size_t)n * D_ + tid * 4);
    float ss = v.x * v.x + v.y * v.y + v.z * v.z + v.w * v.w;
#pragma unroll
    for (int m = 1; m < 64; m <<= 1) ss += __shfl_xor(ss, m);
    __shared__ float red[4];
    if ((tid & 63) == 0) red[tid >> 6] = ss;
    __syncthreads();
    const float tot = red[0] + red[1] + red[2] + red[3];
    const float rstd = rsqrtf(tot * (1.0f / D_) + 1e-6f);
    const float4 wv = *(const float4*)(w + tid * 4);
    union { bf16 h[4]; uint2 u; } pk;
    pk.h[0] = f2b(v.x * rstd * wv.x);
    pk.h[1] = f2b(v.y * rstd * wv.y);
    pk.h[2] = f2b(v.z * rstd * wv.z);
    pk.h[3] = f2b(v.w * rstd * wv.w);
    *(uint2*)(out + (size_t)n * D_ + tid * 4) = pk.u;
}

// ---------------------------------------------------------------------------
// GEMM: C[M][N] = A[M][K] * Bt[N][K]^T  (A,Bt bf16 row-major; acc fp32)
// 128x128 tile, BK=32, 512 threads = 8 waves (2Mx4N), 64x32/wave.
// PROVEN 353us config (R10): acc = 2x f32x16 = 32 regs; LDS 32 KB.
// Counted-vmcnt depth-1: issue next tile (1 A + 1 B gload/thread), vmcnt(2),
// s_barrier, compute (4x mfma_32x32x16), s_barrier. Source-granule swz4.
// C layout (m74/m101): row=(i&3)+8*(i>>2)+4*(lane>>5), col=lane&31.
// XCD swizzle ONLY for MODE==0 (grouped early-exit + swizzle = R4/R5 bug).
// EPI: 0 = store bf16, 1 = store fp32, 2 = fp32 resid add,
//      3 = swiglu pair -> bf16, 4 = fused RoPE (qkv layout, ldc=3072)
// MODE: 0 = plain, 1 = grouped+gathered A rows (token_list), 2 = grouped contiguous
// ---------------------------------------------------------------------------
template<int EPI, int MODE>
__global__ __launch_bounds__(512)
void gemm_bt(const bf16* __restrict__ A, const bf16* __restrict__ Bt,
             void* __restrict__ Cout, const float* __restrict__ resid,
             int M, int Kdim, int lda, int ldb, int ldc, long bstride,
             const int* __restrict__ tlist, const int* __restrict__ offs,
             const float* __restrict__ fc, const float* __restrict__ fs)
{
    __shared__ bf16 As[2][128 * 32];
    __shared__ bf16 Bs[2][128 * 32];
    const int tid = threadIdx.x;
    const int wave = tid >> 6, lane = tid & 63;

    int bx, by;
    if constexpr (MODE == 0) {
        const int gx = gridDim.x;
        const int nwg = gx * gridDim.y;
        int flat = blockIdx.y * gx + blockIdx.x;
        flat = (flat & 7) * (nwg >> 3) + (flat >> 3);
        bx = flat % gx; by = flat / gx;
    } else {
        bx = blockIdx.x; by = blockIdx.y;
    }

    int mcount = M, outBase = 0;
    const bf16* Bp = Bt;
    if (MODE != 0) {
        const int e = blockIdx.z;
        outBase = offs[e];
        mcount = offs[e + 1] - outBase;
        Bp = Bt + (size_t)e * bstride;
    }
    const int m0 = by * 128;
    if (m0 >= mcount) return;
    const int n0 = bx * 128;

    // staging: 1 A-load + 1 B-load per thread. row = tid>>2 (0..127),
    // LDS slot granule = tid&3; SOURCE granule pre-swizzled (slot^swz4(row)).
    // LDS dest byte = row*64 + slot*16 = tid*16 = wave*1024 + lane*16 (linear).
    const int srow = tid >> 2;
    const int sc4 = tid & 3;
    const int scol = (sc4 ^ swz4(srow)) * 8;
    int rA = m0 + srow;
    if (rA >= mcount) rA = mcount - 1;
    long arow;
    if (MODE == 1)      arow = tlist[outBase + rA];
    else if (MODE == 2) arow = (long)outBase + rA;
    else                arow = rA;
    const bf16* aptr = A + (size_t)arow * lda + scol;
    const bf16* bptr = Bp + (size_t)(n0 + srow) * ldb + scol;

    f32x16 acc[2];
#pragma unroll
    for (int tm = 0; tm < 2; tm++)
#pragma unroll
        for (int i = 0; i < 16; i++) acc[tm][i] = 0.f;

    const int wm = (wave >> 2) * 64, wn = (wave & 3) * 32;
    const int l31 = lane & 31, l5 = lane >> 5;

    // fragment LDS element offsets (slot = granule ^ swz4(row))
    int aoff[2][2], boff[2];
#pragma unroll
    for (int tm = 0; tm < 2; tm++) {
        const int ra = wm + tm * 32 + l31;
#pragma unroll
        for (int kk = 0; kk < 2; kk++)
            aoff[tm][kk] = ra * 32 + ((kk * 2 + l5) ^ swz4(ra)) * 8;
    }
    {
        const int rb = wn + l31;
#pragma unroll
        for (int kk = 0; kk < 2; kk++)
            boff[kk] = rb * 32 + ((kk * 2 + l5) ^ swz4(rb)) * 8;
    }

    const int nkt = Kdim >> 5;
    // prologue: stage tile 0 into buffer 0
    gload_lds16(aptr, (char*)&As[0][0] + wave * 1024);
    gload_lds16(bptr, (char*)&Bs[0][0] + wave * 1024);

    int p = 0;
    for (int kt = 0; kt < nkt; kt++) {
        if (kt + 1 < nkt) {
            const int ko = (kt + 1) << 5;
            gload_lds16(aptr + ko, (char*)&As[p ^ 1][0] + wave * 1024);
            gload_lds16(bptr + ko, (char*)&Bs[p ^ 1][0] + wave * 1024);
            asm volatile("s_waitcnt vmcnt(2)" ::: "memory");   // FIFO: current buffer landed
        } else {
            asm volatile("s_waitcnt vmcnt(0)" ::: "memory");
        }
        asm volatile("s_barrier" ::: "memory");

        const bf16* Ab = &As[p][0];
        const bf16* Bb = &Bs[p][0];
#pragma unroll
        for (int kk = 0; kk < 2; kk++) {
            const bf16x8 bf0 = ld_bf16x8(&Bb[boff[kk]]);
            const bf16x8 af0 = ld_bf16x8(&Ab[aoff[0][kk]]);
            const bf16x8 af1 = ld_bf16x8(&Ab[aoff[1][kk]]);
            acc[0] = __builtin_amdgcn_mfma_f32_32x32x16_bf16(af0, bf0, acc[0], 0, 0, 0);
            acc[1] = __builtin_amdgcn_mfma_f32_32x32x16_bf16(af1, bf0, acc[1], 0, 0, 0);
        }

        asm volatile("s_barrier" ::: "memory");
        p ^= 1;
    }

    // epilogue: row = (i&3) + 8*(i>>2) + 4*l5, col = l31 within each 32x32 tile
#pragma unroll
    for (int tm = 0; tm < 2; tm++)
#pragma unroll
        for (int i = 0; i < 16; i++) {
            const int r = m0 + wm + tm * 32 + (i & 3) + 8 * (i >> 2) + 4 * l5;
            const int c = n0 + wn + l31;
            const float v = acc[tm][i];
            if (EPI == 3) {
                const float other = __shfl_xor(v, 1);
                const float res = (v / (1.f + __expf(-v))) * other;  // silu(g1)*g3 on even lanes
                if (((lane & 1) == 0) && r < mcount)
                    ((bf16*)Cout)[(size_t)(outBase + r) * ldc + (c >> 1)] = f2b(res);
            } else if (EPI == 4) {
                // fused RoPE: c<1024 q (scale 1/8), c<2048 k, else v passthrough
                const float other = __shfl_xor(v, 1);
                float o = v;
                if (c < 2048) {
                    const int s = r & (S_ - 1);
                    const int jf = (c & 63) >> 1;
                    const float co = fc[s * 32 + jf], si = fs[s * 32 + jf];
                    o = v * co + other * ((c & 1) ? si : -si);
                    if (c < 1024) o *= 0.125f;   // fold 1/sqrt(HD) into q
                }
                ((bf16*)Cout)[(size_t)r * ldc + c] = f2b(o);
            } else if (r < mcount) {
                const size_t oi = (size_t)(outBase + r) * ldc + c;
                if (EPI == 0)      ((bf16*)Cout)[oi] = f2b(v);
                else if (EPI == 1) ((float*)Cout)[oi] = v;
                else               ((float*)Cout)[oi] = resid[oi] + v;
            }
        }
}

// ---------------------------------------------------------------------------
// Flash attention, non-causal, swapped-operand structure.
// grid (S/128, H=16, B=2), block 256 (4 waves, 32 q-rows/wave). KV tile = 64.
// ---------------------------------------------------------------------------
__global__ __launch_bounds__(256)
void attn_kernel(const bf16* __restrict__ qkv, bf16* __restrict__ out)
{
    __shared__ __align__(16) bf16 Ks[64 * 72];          // [kv][64 hd] pad 72
    __shared__ __align__(16) bf16 Vs[4 * 1032 + 8];     // [hd chunk][64 kv][16 hd], chunk stride 1032
    const int tid = threadIdx.x, wave = tid >> 6, lane = tid & 63;
    const int b = blockIdx.z, hh = blockIdx.y;
    const int q0 = blockIdx.x * 128;
    const bf16* base  = qkv + ((size_t)b * S_) * 3072 + (size_t)hh * 64;
    const bf16* kbase = base + 1024;
    const bf16* vbase = base + 2048;
    const int fr = lane & 15, fg = lane >> 4;

    // Q fragments (B-operand): lane holds q = fr, hd = fg*8.. (+32 per s2)
    bf16x8 aq[2][2];
#pragma unroll
    for (int qb = 0; qb < 2; qb++)
#pragma unroll
        for (int s2 = 0; s2 < 2; s2++)
            aq[qb][s2] = ld_bf16x8(base + (size_t)(q0 + wave * 32 + qb * 16 + fr) * 3072 + s2 * 32 + fg * 8);

    f32x4 zero4 = {0.f, 0.f, 0.f, 0.f};
    f32x4 acc_o[2][4];       // [qb][hf]: rows q = fg*4+j, cols hd = hf*16+fr
    float mrow[2], lrow[2];  // per-lane stats for q = fr
#pragma unroll
    for (int qb = 0; qb < 2; qb++) {
#pragma unroll
        for (int hf = 0; hf < 4; hf++) acc_o[qb][hf] = zero4;
        mrow[qb] = -1e30f; lrow[qb] = 0.f;
    }

    const int srow = tid >> 2, sc4 = tid & 3;
    const unsigned vtr0 =
        (unsigned)(uintptr_t)(__attribute__((address_space(3))) void*)&Vs[0] + lane * 8;

    // register-staged K/V prefetch (double-buffered against compute)
    uint4 kg0, kg1, vg0, vg1;
    {
        const bf16* kr = kbase + (size_t)srow * 3072 + sc4 * 16;
        kg0 = *(const uint4*)kr; kg1 = *(const uint4*)(kr + 8);
        const bf16* vr = vbase + (size_t)srow * 3072 + sc4 * 16;
        vg0 = *(const uint4*)vr; vg1 = *(const uint4*)(vr + 8);
    }

    for (int kv0 = 0; kv0 < S_; kv0 += 64) {
        __syncthreads();
        *(uint4*)&Ks[srow * 72 + sc4 * 16]         = kg0;
        *(uint4*)&Ks[srow * 72 + sc4 * 16 + 8]     = kg1;
        *(uint4*)&Vs[sc4 * 1032 + srow * 16]       = vg0;
        *(uint4*)&Vs[sc4 * 1032 + srow * 16 + 8]   = vg1;
        __syncthreads();
        if (kv0 + 64 < S_) {    // prefetch next tile (hides HBM under compute)
            const bf16* kr = kbase + (size_t)(kv0 + 64 + srow) * 3072 + sc4 * 16;
            kg0 = *(const uint4*)kr; kg1 = *(const uint4*)(kr + 8);
            const bf16* vr = vbase + (size_t)(kv0 + 64 + srow) * 3072 + sc4 * 16;
            vg0 = *(const uint4*)vr; vg1 = *(const uint4*)(vr + 8);
        }

        // ---- QK^T (swapped): sc[kt][qb] = K_tile(kt) x Q(qb), S^T layout ----
        f32x4 sc[4][2];
#pragma unroll
        for (int kt = 0; kt < 4; kt++)
#pragma unroll
            for (int qb = 0; qb < 2; qb++) sc[kt][qb] = zero4;
        __builtin_amdgcn_s_setprio(1);
#pragma unroll
        for (int kt = 0; kt < 4; kt++) {
            const bf16x8 k0 = ld_bf16x8(&Ks[(kt * 16 + fr) * 72 + fg * 8]);
            const bf16x8 k1 = ld_bf16x8(&Ks[(kt * 16 + fr) * 72 + 32 + fg * 8]);
#pragma unroll
            for (int qb = 0; qb < 2; qb++) {
                sc[kt][qb] = __builtin_amdgcn_mfma_f32_16x16x32_bf16(k0, aq[qb][0], sc[kt][qb], 0, 0, 0);
                sc[kt][qb] = __builtin_amdgcn_mfma_f32_16x16x32_bf16(k1, aq[qb][1], sc[kt][qb], 0, 0, 0);
            }
        }
        __builtin_amdgcn_s_setprio(0);

        // ---- online softmax, fully in-register (lane owns row q = fr) ----
        bf16x8 pcomb[2][2];   // [qb][tp]: A-operand P fragments (two 16-kv tiles packed)
        float scalv[2];
#pragma unroll
        for (int qb = 0; qb < 2; qb++) {
            float pm = -1e30f;
#pragma unroll
            for (int kt = 0; kt < 4; kt++)
#pragma unroll
                for (int j = 0; j < 4; j++) pm = fmaxf(pm, sc[kt][qb][j]);
            pm = fmaxf(pm, __shfl_xor(pm, 16));
            pm = fmaxf(pm, __shfl_xor(pm, 32));
            const float mnew = fmaxf(mrow[qb], pm);
            const float scal = __expf(mrow[qb] - mnew);
            mrow[qb] = mnew;
            float ps = 0.f;
            union { bf16 h[16]; bf16x8 v8[2]; } pk;
#pragma unroll
            for (int kt = 0; kt < 4; kt++)
#pragma unroll
                for (int j = 0; j < 4; j++) {
                    const float p = __expf(sc[kt][qb][j] - mnew);
                    ps += p;
                    pk.h[kt * 4 + j] = f2b(p);
                }
            pcomb[qb][0] = pk.v8[0];
            pcomb[qb][1] = pk.v8[1];
            ps += __shfl_xor(ps, 16);
            ps += __shfl_xor(ps, 32);
            lrow[qb] = lrow[qb] * scal + ps;
            scalv[qb] = scal;
        }

        // rescale O (its rows are q = fg*4+j -> fetch that q's scal)
#pragma unroll
        for (int j = 0; j < 4; j++) {
            const int src = (lane & 48) + fg * 4 + j;
            const float s0 = __shfl(scalv[0], src);
            const float s1 = __shfl(scalv[1], src);
#pragma unroll
            for (int hf = 0; hf < 4; hf++) {
                acc_o[0][hf][j] *= s0;
                acc_o[1][hf][j] *= s1;
            }
        }

        // ---- PV: B-operand via hw transpose-read, two 16-kv tiles per mfma ----
#pragma unroll
        for (int tp = 0; tp < 2; tp++) {
            union { u32x2 d2[2]; bf16x8 v8; } vc[4];
#pragma unroll
            for (int hf = 0; hf < 4; hf++) {
                vc[hf].d2[0] = tr16_read(vtr0 + hf * 2064 + (tp * 2)     * 512);
                vc[hf].d2[1] = tr16_read(vtr0 + hf * 2064 + (tp * 2 + 1) * 512);
            }
            asm volatile("s_waitcnt lgkmcnt(0)" ::: "memory");
            __builtin_amdgcn_sched_barrier(0);   // rule 18: keep MFMAs below the wait
            __builtin_amdgcn_s_setprio(1);
#pragma unroll
            for (int hf = 0; hf < 4; hf++)
#pragma unroll
                for (int qb = 0; qb < 2; qb++)
                    acc_o[qb][hf] = __builtin_amdgcn_mfma_f32_16x16x32_bf16(
                        pcomb[qb][tp], vc[hf].v8, acc_o[qb][hf], 0, 0, 0);
            __builtin_amdgcn_s_setprio(0);
        }
    }

    // ---- epilogue: out rows q = fg*4+j, cols hd = hf*16+fr ----
#pragma unroll
    for (int qb = 0; qb < 2; qb++) {
        const float inv = 1.f / lrow[qb];
#pragma unroll
        for (int j = 0; j < 4; j++) {
            const float ij = __shfl(inv, (lane & 48) + fg * 4 + j);
            const int r = q0 + wave * 32 + qb * 16 + fg * 4 + j;
#pragma unroll
            for (int hf = 0; hf < 4; hf++)
                out[((size_t)(b * S_ + r)) * D_ + hh * 64 + hf * 16 + fr] =
                    f2b(acc_o[qb][hf][j] * ij);
        }
    }
}

// ---------------------------------------------------------------------------
// MoE gating + FUSED second RMSNorm. One wave per token: computes sum-of-
// squares + expert scores in one pass, keeps x*w products in registers
// (static xs[4][4] -> no scratch, rule 20), then writes xn = bf16(x*w*rstd)
// from all lanes and does top-2 on lane 0. Replaces rmsnorm#2 + gating.
// ---------------------------------------------------------------------------
__global__ __launch_bounds__(256)
void gating_kernel(const float* __restrict__ h, const float* __restrict__ gw,
                   const float* __restrict__ wnorm, bf16* __restrict__ xout,
                   int* __restrict__ top_idx, float* __restrict__ top_w)
{
    const int wave = threadIdx.x >> 6, lane = threadIdx.x & 63;
    const int n = blockIdx.x * 4 + wave;
    const float* hr = h + (size_t)n * D_;
    float acc[8] = {0.f, 0.f, 0.f, 0.f, 0.f, 0.f, 0.f, 0.f};
    float ss = 0.f;
    float xs[4][4];
#pragma unroll
    for (int it = 0; it < 4; it++) {
        const int d = lane * 4 + it * 256;
        const float4 hv = *(const float4*)(hr + d);
        const float4 wv = *(const float4*)(wnorm + d);
        ss += hv.x * hv.x + hv.y * hv.y + hv.z * hv.z + hv.w * hv.w;
        xs[it][0] = hv.x * wv.x; xs[it][1] = hv.y * wv.y;
        xs[it][2] = hv.z * wv.z; xs[it][3] = hv.w * wv.w;
#pragma unroll
        for (int e2 = 0; e2 < 8; e2++) {
            const float4 gv = *(const float4*)(gw + e2 * D_ + d);
            acc[e2] += xs[it][0] * gv.x + xs[it][1] * gv.y + xs[it][2] * gv.z + xs[it][3] * gv.w;
        }
    }
#pragma unroll
    for (int m = 1; m < 64; m <<= 1) {
        ss += __shfl_xor(ss, m);
#pragma unroll
        for (int e2 = 0; e2 < 8; e2++) acc[e2] += __shfl_xor(acc[e2], m);
    }
    const float rstd = rsqrtf(ss * (1.0f / D_) + 1e-6f);
    // fused rmsnorm output (formerly a separate kernel pass over hbuf)
#pragma unroll
    for (int it = 0; it < 4; it++) {
        const int d = lane * 4 + it * 256;
        union { bf16 hh[4]; uint2 u; } pk;
#pragma unroll
        for (int j = 0; j < 4; j++) pk.hh[j] = f2b(xs[it][j] * rstd);
        *(uint2*)(xout + (size_t)n * D_ + d) = pk.u;
    }
    if (lane == 0) {
        float s[8];
#pragma unroll
        for (int e2 = 0; e2 < 8; e2++) s[e2] = acc[e2] * rstd;
        int e0 = 0;
#pragma unroll
        for (int e2 = 1; e2 < 8; e2++) if (s[e2] > s[e0]) e0 = e2;
        int e1 = (e0 == 0) ? 1 : 0;
#pragma unroll
        for (int e2 = 0; e2 < 8; e2++) if (e2 != e0 && s[e2] > s[e1]) e1 = e2;
        const float mx = s[e0];
        float Z = 0.f;
        float p[8];
#pragma unroll
        for (int e2 = 0; e2 < 8; e2++) { p[e2] = __expf(s[e2] - mx); Z += p[e2]; }
        const float v0 = p[e0] / Z, v1 = p[e1] / Z;
        const float sm = v0 + v1 + 1e-9f;
        top_idx[n * 2] = e0; top_idx[n * 2 + 1] = e1;
        top_w[n * 2] = v0 / sm; top_w[n * 2 + 1] = v1 / sm;
    }
}

// ---------------------------------------------------------------------------
// Routing: single block, LDS atomics only. histogram -> offsets -> scatter.
// Adds the shared expert as slot 8: identity token list for all 4096 tokens.
// ---------------------------------------------------------------------------
__global__ __launch_bounds__(1024)
void route_kernel(const int* __restrict__ top_idx, int* __restrict__ offs,
                  int* __restrict__ token_list, int* __restrict__ tok_pos)
{
    __shared__ int hist[8];
    __shared__ int base[8];
    const int tid = threadIdx.x;
    if (tid < 8) hist[tid] = 0;
    __syncthreads();
    int4 e4a = *(const int4*)(top_idx + tid * 8);
    int4 e4b = *(const int4*)(top_idx + tid * 8 + 4);
    int myidx[8] = {e4a.x, e4a.y, e4a.z, e4a.w, e4b.x, e4b.y, e4b.z, e4b.w};
#pragma unroll
    for (int i = 0; i < 8; i++) atomicAdd(&hist[myidx[i]], 1);
    __syncthreads();
    if (tid == 0) {
        int o = 0;
#pragma unroll
        for (int e = 0; e < 8; e++) { base[e] = o; offs[e] = o; o += hist[e]; }
        offs[8] = o;          // == 8192 always
        offs[9] = o + N_;     // shared-expert segment
    }
    __syncthreads();
    if (tid < 8) hist[tid] = 0;
    __syncthreads();
#pragma unroll
    for (int i = 0; i < 8; i++) {
        const int entry = tid * 8 + i;
        const int e = myidx[i];
        const int pos = base[e] + atomicAdd(&hist[e], 1);
        token_list[pos] = entry >> 1;
        tok_pos[entry] = pos;
    }
    // shared expert (slot 8): identity gather over all tokens
#pragma unroll
    for (int i = 0; i < 4; i++)
        token_list[2 * N_ + tid * 4 + i] = tid * 4 + i;
}

// out = h + eo[shared(n)] + w0*eo[pos0] + w1*eo[pos1]
__global__ __launch_bounds__(256)
void combine_kernel(const float* __restrict__ h, const bf16* __restrict__ eo,
                    const int* __restrict__ tok_pos, const float* __restrict__ top_w,
                    float* __restrict__ out)
{
    const int idx = blockIdx.x * 256 + threadIdx.x;   // N_*D_/4 total
    const int n = idx >> 8;
    const int c = (idx & 255) * 4;
    const float4 hv = *(const float4*)(h + (size_t)n * D_ + c);
    const int p0 = tok_pos[n * 2], p1 = tok_pos[n * 2 + 1];
    const float w0 = top_w[n * 2], w1 = top_w[n * 2 + 1];
    union { uint2 u; bf16 hh[4]; } a0, a1, ash;
    a0.u  = *(const uint2*)(eo + (size_t)p0 * D_ + c);
    a1.u  = *(const uint2*)(eo + (size_t)p1 * D_ + c);
    ash.u = *(const uint2*)(eo + (size_t)(2 * N_ + n) * D_ + c);
    float4 r;
    r.x = hv.x + b2f(ash.hh[0]) + w0 * b2f(a0.hh[0]) + w1 * b2f(a1.hh[0]);
    r.y = hv.y + b2f(ash.hh[1]) + w0 * b2f(a0.hh[1]) + w1 * b2f(a1.hh[1]);
    r.z = hv.z + b2f(ash.hh[2]) + w0 * b2f(a0.hh[2]) + w1 * b2f(a1.hh[2]);
    r.w = hv.w + b2f(ash.hh[3]) + w0 * b2f(a0.hh[3]) + w1 * b2f(a1.hh[3]);
    *(float4*)(out + (size_t)n * D_ + c) = r;
}

// ---------------------------------------------------------------------------
extern "C" void kernel_launch(void* const* d_in, const int* in_sizes, int n_in,
                              void* d_out, int out_size, void* d_ws, size_t ws_size,
                              hipStream_t stream)
{
    const float* x   = (const float*)d_in[0];
    const float* fc  = (const float*)d_in[1];
    const float* fs  = (const float*)d_in[2];
    const float* anw = (const float*)d_in[3];
    const float* fnw = (const float*)d_in[4];
    const float* wq  = (const float*)d_in[5];
    const float* wk  = (const float*)d_in[6];
    const float* wv  = (const float*)d_in[7];
    const float* wo  = (const float*)d_in[8];
    const float* gw  = (const float*)d_in[9];
    const float* ew1 = (const float*)d_in[10];
    const float* ew2 = (const float*)d_in[11];
    const float* ew3 = (const float*)d_in[12];
    const float* sw1 = (const float*)d_in[13];
    const float* sw2 = (const float*)d_in[14];
    const float* sw3 = (const float*)d_in[15];

    char* ws = (char*)d_ws;
    bf16*  wqkv_t = (bf16*)(ws + 0);           //  6291456 B  [3072][1024]
    bf16*  wo_t   = (bf16*)(ws + 6291456);     //  2097152 B  [1024][1024]
    bf16*  ew13_t = (bf16*)(ws + 8388608);     // 37748736 B  9 x [2048][1024] interleaved (slot 8 = shared sw1/sw3)
    bf16*  ew2_t  = (bf16*)(ws + 46137344);    // 18874368 B  9 x [1024][1024] (slot 8 = shared sw2)
    bf16*  xn     = (bf16*)(ws + 65011712);    //  8388608 B  [4096][1024]  (reused as xf)
    bf16*  qkv    = (bf16*)(ws + 73400320);    // 25165824 B  [4096][3072]  (reused as h1 [12288][1024])
    bf16*  attn   = (bf16*)(ws + 98566144);    //  8388608 B  [4096][1024]
    float* hbuf   = (float*)(ws + 106954752);  // 16777216 B  [4096][1024]
    bf16*  eo     = (bf16*)(ws + 123731968);   // 25165824 B  [12288][1024]
    char*  misc   = ws + 148897792;
    int*   offs       = (int*)(misc + 0);              // 16 ints
    int*   top_idx    = (int*)(misc + 128);            // 8192 ints
    float* top_w      = (float*)(misc + 128 + 32768);  // 8192 floats
    int*   token_list = (int*)(misc + 128 + 65536);    // 12288 ints
    int*   tok_pos    = (int*)(misc + 128 + 131072);   // 8192 ints

    const dim3 tb(256);
    const dim3 tb512(512);
    // all weight transposes in one launch (64x64 tiles)
    transpose_all<<<dim3(16, 16, 31), tb, 0, stream>>>(
        wq, wk, wv, wo, ew1, ew2, ew3, sw1, sw2, sw3,
        wqkv_t, wo_t, ew13_t, ew2_t);

    // attention branch (RoPE fused into QKV epilogue)
    rmsnorm_kernel<<<N_, tb, 0, stream>>>(x, anw, xn);
    gemm_bt<4, 0><<<dim3(24, 32, 1), tb512, 0, stream>>>(xn, wqkv_t, qkv, nullptr,
        N_, 1024, 1024, 1024, 3072, 0, nullptr, nullptr, fc, fs);
    attn_kernel<<<dim3(16, 16, 2), tb, 0, stream>>>(qkv, attn);
    gemm_bt<2, 0><<<dim3(8, 32, 1), tb512, 0, stream>>>(attn, wo_t, hbuf, x,
        N_, 1024, 1024, 1024, 1024, 0, nullptr, nullptr, nullptr, nullptr);

    // FFN branch (rmsnorm#2 fused into gating: writes xn AND top-2 routing)
    gating_kernel<<<N_ / 4, tb, 0, stream>>>(hbuf, gw, fnw, xn, top_idx, top_w);
    route_kernel<<<1, 1024, 0, stream>>>(top_idx, offs, token_list, tok_pos);

    // experts (routed top-2 + shared as slot 8): h1 = silu(xg@w1)*(xg@w3); eo = h1@w2
    gemm_bt<3, 1><<<dim3(16, 32, 9), tb512, 0, stream>>>(xn, ew13_t, qkv, nullptr,
        0, 1024, 1024, 1024, 1024, 2097152, token_list, offs, nullptr, nullptr);   // qkv = h1 now
    gemm_bt<0, 2><<<dim3(8, 32, 9), tb512, 0, stream>>>((const bf16*)qkv, ew2_t, eo, nullptr,
        0, 1024, 1024, 1024, 1024, 1048576, nullptr, offs, nullptr, nullptr);

    combine_kernel<<<4096, tb, 0, stream>>>(hbuf, eo, tok_pos, top_w, (float*)d_out);
}